// Round 1
// baseline (985.693 us; speedup 1.0000x reference)
//
#include <hip/hip_runtime.h>
#include <math.h>

// ---------------------------------------------------------------------------
// AFNO2D as 5 bf16-MFMA GEMM stages + constant bake.
//   x:[1,768,180,360] f32. rfft2(ortho) -> per-mode blockdiag complex MLP
//   (8 blocks x 96ch, relu, softshrink, W-modes y<91 kept) -> irfft2 + x.
//
// GEMM forms (D = A*B, mfma_f32_16x16x32_bf16):
//  gA : per (c, h-half): D[m=h(96)][n=(s*96+y)(192)] = x-rows(K=384) * BA
//       store transposed -> G1[c][y][s*180+h]        (regs = 4 consecutive h)
//  gHf: per c: D[m=(s*192+h')(384)][n=y(96)] = BH(A) * G1-rows(B, K=384)
//       store -> F2[c2=2c+s][y*180+h']               (regs = 4 consecutive h')
//  gC : per (kb, 64-mode tile): Act(LDS-transposed from F2) * BW1 -> relu
//       -> *BW2 -> softshrink, store -> F3[cout][y][s'*180+h'] (4 consec h')
//  gHi: per c: D[m=y(96)][n=(s*192+h)(384)] = F3-rows(A) * BHI(B)
//       store -> Spec[(c*180+h)][s*96+y]             (regs = 4 consecutive y)
//  gE : per 64-row tile, ROLE-SWAPPED: D[m=w(384)][n=row(64)] =
//       BE-rows(A) * Spec-rows(B, K=192); lane holds 4 consecutive w ->
//       float4 x-load + float4 store. 8 waves/block.
// Fragment layouts used (guide-verified): A[m=l&15][k=q*8+j],
// B[k=q*8+j][n=l&15], C/D[row=q*4+reg][col=l&15].
// ---------------------------------------------------------------------------

#define R360f 0.05270462766947299f   // 1/sqrt(360)
#define R180f 0.07453559924999299f   // 1/sqrt(180)
#define LAM   0.01f

typedef short v8s __attribute__((ext_vector_type(8)));
typedef float v4f __attribute__((ext_vector_type(4)));

#define MFMA(a,b,c) __builtin_amdgcn_mfma_f32_16x16x32_bf16(a,b,c,0,0,0)

// ws layout (shorts): BUF1 | BUF2 | BA | BH | BHI | BW1 | BW2 | BE
#define NBUF  26542080              // 53,084,160 B per ping-pong buffer
#define OBA   (2*NBUF)
#define OBH   (OBA + 73728)         // BA  [192][384]
#define OBHI  (OBH + 147456)        // BH  [384][384]
#define OBW1  (OBHI + 147456)       // BHI [384][384]
#define OBW2  (OBW1 + 294912)       // BW1 [8][192][192]
#define OBE   (OBW2 + 294912)       // BW2 [8][192][192]
#define NBAKE 1032192               // + BE [384][192]

static __device__ __forceinline__ short f2bs(float f){   // f32 -> bf16 (RNE)
    unsigned u = __builtin_bit_cast(unsigned, f);
    u = (u + 0x7fffu + ((u >> 16) & 1u)) >> 16;
    return (short)u;
}
static __device__ __forceinline__ v8s ld8(const short* p){
    return __builtin_bit_cast(v8s, *(const uint4*)p);
}
union PK { short s[4]; uint2 u; };
static __device__ __forceinline__ uint2 pk4(v4f a){
    PK t; t.s[0]=f2bs(a[0]); t.s[1]=f2bs(a[1]); t.s[2]=f2bs(a[2]); t.s[3]=f2bs(a[3]);
    return t.u;
}
union S8 { uint4 u; short s[8]; v8s v; };
static __device__ __forceinline__ float sshrink(float v){
    return (v > LAM) ? (v - LAM) : ((v < -LAM) ? (v + LAM) : 0.f);
}

// ---------------------------------------------------------------------------
__global__ __launch_bounds__(256) void bake(const float* __restrict__ w1,
                                            const float* __restrict__ w2,
                                            short* __restrict__ bt){
    int idx = blockIdx.x*256 + threadIdx.x;
    if (idx >= NBAKE) return;
    float v = 0.f;
    if (idx < 73728){                               // BA (B-role) [n=s*96+y][k=w]
        int n = idx/384, k = idx - n*384;
        int s = n >= 96, y = n - s*96;
        if (y < 91 && k < 360){
            float th = (float)((k*y) % 360) * 0.017453292519943295f;
            float sv, cv; sincosf(th, &sv, &cv);
            v = s ? -sv*R360f : cv*R360f;           // e^{-i th}
        }
        bt[OBA + idx] = f2bs(v); return;
    }
    idx -= 73728;
    if (idx < 147456){                              // BH (A-role) [m=s*192+h'][k=si*180+h]
        int m = idx/384, k = idx - m*384;
        int s = m >= 192, hp = m - s*192;
        if (hp < 180 && k < 360){
            int si = k >= 180; int h = k - si*180;
            float th = (float)((h*hp) % 180) * 0.03490658503988659f;
            float sv, cv; sincosf(th, &sv, &cv);
            v = R180f * (s == 0 ? (si == 0 ? cv : sv) : (si == 0 ? -sv : cv));
        }
        bt[OBH + idx] = f2bs(v); return;
    }
    idx -= 147456;
    if (idx < 147456){                              // BHI (B-role) [n=s*192+h][k=sp*180+h']
        int n = idx/384, k = idx - n*384;
        int s = n >= 192, h = n - s*192;
        if (h < 180 && k < 360){
            int sp = k >= 180; int hp = k - sp*180;
            float th = (float)((h*hp) % 180) * 0.03490658503988659f;
            float sv, cv; sincosf(th, &sv, &cv);
            v = R180f * (s == 0 ? (sp == 0 ? cv : -sv) : (sp == 0 ? sv : cv));
        }
        bt[OBHI + idx] = f2bs(v); return;
    }
    idx -= 147456;
    if (idx < 294912){                              // BW1 (B-role) [kb][n=2o+sp][k=2i+si]
        int kb = idx / 36864; int r = idx - kb*36864;
        int n = r / 192, k = r - n*192;
        int o = n >> 1, sp = n & 1, i = k >> 1, si = k & 1;
        const float* wp = w1 + ((((kb*96 + i)*96) + o) << 1);
        v = sp == 0 ? (si == 0 ? wp[0] : -wp[1]) : (si == 0 ? wp[1] : wp[0]);
        bt[OBW1 + idx] = f2bs(v); return;
    }
    idx -= 294912;
    if (idx < 294912){                              // BW2
        int kb = idx / 36864; int r = idx - kb*36864;
        int n = r / 192, k = r - n*192;
        int o = n >> 1, sp = n & 1, i = k >> 1, si = k & 1;
        const float* wp = w2 + ((((kb*96 + i)*96) + o) << 1);
        v = sp == 0 ? (si == 0 ? wp[0] : -wp[1]) : (si == 0 ? wp[1] : wp[0]);
        bt[OBW2 + idx] = f2bs(v); return;
    }
    idx -= 294912;
    {                                               // BE [w(384)][k=s*96+y]
        int w = idx / 192, k = idx - w*192;
        int s = k >= 96, y = k - s*96;
        if (w < 360 && y < 91){
            float th = (float)((y*w) % 360) * 0.017453292519943295f;
            float sv, cv; sincosf(th, &sv, &cv);
            v = (s == 0) ? (y == 0 ? 1.f : 2.f) * cv * R360f
                         : (y == 0 ? 0.f : -2.f*sv*R360f);
        }
        bt[OBE + idx] = f2bs(v);
    }
}

// ---------------------------------------------------------------------------
__global__ __launch_bounds__(256) void gA(const float* __restrict__ x,
                                          short* __restrict__ G1,
                                          const short* __restrict__ BA){
    const int b = blockIdx.x, c = b >> 1, hh = (b & 1)*96;
    const int tid = threadIdx.x, wid = tid >> 6, lane = tid & 63;
    const int l15 = lane & 15, q8 = (lane >> 4) << 3, q4 = q8 >> 1;
    const int nt0 = wid*3;
    const v4f vz = {0.f,0.f,0.f,0.f};
    v4f acc[6][3];
    #pragma unroll
    for (int i=0;i<6;++i){ acc[i][0]=vz; acc[i][1]=vz; acc[i][2]=vz; }
    for (int ks=0; ks<12; ++ks){
        const int k0 = ks*32;
        int kk = k0 + q8; if (kk >= 360) kk = 0;   // garbage * zero B-rows
        v8s af[6];
        #pragma unroll
        for (int mt=0; mt<6; ++mt){
            int h = hh + mt*16 + l15; if (h > 179) h = 179;  // rows>=180 dropped at store
            const float* xp = x + (c*180 + h)*360 + kk;
            float4 f0 = *(const float4*)xp;
            float4 f1 = *(const float4*)(xp + 4);
            S8 tt;
            tt.s[0]=f2bs(f0.x); tt.s[1]=f2bs(f0.y); tt.s[2]=f2bs(f0.z); tt.s[3]=f2bs(f0.w);
            tt.s[4]=f2bs(f1.x); tt.s[5]=f2bs(f1.y); tt.s[6]=f2bs(f1.z); tt.s[7]=f2bs(f1.w);
            af[mt] = tt.v;
        }
        v8s bf[3];
        #pragma unroll
        for (int j=0;j<3;++j)
            bf[j] = ld8(BA + ((nt0+j)*16 + l15)*384 + k0 + q8);
        #pragma unroll
        for (int mt=0; mt<6; ++mt)
            #pragma unroll
            for (int j=0;j<3;++j)
                acc[mt][j] = MFMA(af[mt], bf[j], acc[mt][j]);
    }
    #pragma unroll
    for (int mt=0; mt<6; ++mt){
        int hg = hh + mt*16 + q4;                   // 4-aligned, never straddles 180
        if (hg >= 180) continue;
        #pragma unroll
        for (int j=0;j<3;++j){
            int n = (nt0+j)*16 + l15;
            int s = n >= 96, y = n - s*96;
            *(uint2*)(G1 + (c*96 + y)*360 + s*180 + hg) = pk4(acc[mt][j]);
        }
    }
}

// ---------------------------------------------------------------------------
__global__ __launch_bounds__(512) void gHf(const short* __restrict__ G1,
                                           short* __restrict__ F2,
                                           const short* __restrict__ BH){
    const int c = blockIdx.x;
    const int tid = threadIdx.x, wid = tid >> 6, lane = tid & 63;
    const int l15 = lane & 15, q8 = (lane >> 4) << 3, q4 = q8 >> 1;
    const int mt0 = wid*3;
    const v4f vz = {0.f,0.f,0.f,0.f};
    v4f acc[3][6];
    #pragma unroll
    for (int i=0;i<3;++i)
        #pragma unroll
        for (int j=0;j<6;++j) acc[i][j]=vz;
    for (int ks=0; ks<12; ++ks){
        const int k0 = ks*32;
        int kk = k0 + q8; if (kk >= 360) kk = 0;
        v8s af[3];
        #pragma unroll
        for (int i=0;i<3;++i)
            af[i] = ld8(BH + ((mt0+i)*16 + l15)*384 + k0 + q8);
        v8s bf[6];
        #pragma unroll
        for (int j=0;j<6;++j)
            bf[j] = ld8(G1 + (c*96 + j*16 + l15)*360 + kk);
        #pragma unroll
        for (int i=0;i<3;++i)
            #pragma unroll
            for (int j=0;j<6;++j)
                acc[i][j] = MFMA(af[i], bf[j], acc[i][j]);
    }
    #pragma unroll
    for (int i=0;i<3;++i){
        int m = (mt0+i)*16 + q4;
        int s = m >= 192, hp = m - s*192;
        if (hp >= 180) continue;
        const int rb = (2*c + s)*17280 + hp;
        #pragma unroll
        for (int j=0;j<6;++j){
            int y = j*16 + l15;
            *(uint2*)(F2 + rb + y*180) = pk4(acc[i][j]);
        }
    }
}

// ---------------------------------------------------------------------------
__global__ __launch_bounds__(256) void gC(const short* __restrict__ F2,
                                          short* __restrict__ F3,
                                          const short* __restrict__ BW1,
                                          const short* __restrict__ BW2,
                                          const float* __restrict__ b1,
                                          const float* __restrict__ b2){
    __shared__ short Act[64*200];    // [mode 64][ch2 192 + 8 pad]
    __shared__ short O1[64*200];
    const int mt = blockIdx.x, kb = blockIdx.y, m0 = mt*64;
    const int tid = threadIdx.x;
    #pragma unroll
    for (int i=0;i<6;++i){           // 1536 16B-chunks: transpose F2 -> Act
        int ch = tid + 256*i;
        int qq = ch / 192, rr = ch - qq*192;
        S8 tt; tt.u = *(const uint4*)(F2 + (kb*192 + rr)*17280 + m0 + qq*8);
        #pragma unroll
        for (int j=0;j<8;++j) Act[(qq*8+j)*200 + rr] = tt.s[j];  // consec lanes -> consec elems
    }
    __syncthreads();
    const int wid = tid >> 6, lane = tid & 63, l15 = lane & 15;
    const int q8 = (lane >> 4) << 3, q4 = q8 >> 1;
    const short* bw1 = BW1 + kb*36864;
    const short* bw2 = BW2 + kb*36864;
    const v4f vz = {0.f,0.f,0.f,0.f};
    v4f a1[12];
    #pragma unroll
    for (int nt=0; nt<12; ++nt) a1[nt]=vz;
    for (int ks=0; ks<6; ++ks){
        int k0 = ks*32;
        v8s af = __builtin_bit_cast(v8s, *(const uint4*)(Act + (wid*16 + l15)*200 + k0 + q8));
        #pragma unroll
        for (int nt=0; nt<12; ++nt)
            a1[nt] = MFMA(af, ld8(bw1 + (nt*16 + l15)*192 + k0 + q8), a1[nt]);
    }
    #pragma unroll
    for (int nt=0; nt<12; ++nt){
        int n = nt*16 + l15;
        float bv = b1[(kb*96 + (n>>1))*2 + (n&1)];
        #pragma unroll
        for (int r=0;r<4;++r)
            O1[(wid*16 + q4 + r)*200 + n] = f2bs(fmaxf(a1[nt][r] + bv, 0.f));
    }
    // wave w wrote exactly rows [w*16, w*16+16) and reads only those: no barrier.
    v4f a2[12];
    #pragma unroll
    for (int nt=0; nt<12; ++nt) a2[nt]=vz;
    for (int ks=0; ks<6; ++ks){
        int k0 = ks*32;
        v8s af = __builtin_bit_cast(v8s, *(const uint4*)(O1 + (wid*16 + l15)*200 + k0 + q8));
        #pragma unroll
        for (int nt=0; nt<12; ++nt)
            a2[nt] = MFMA(af, ld8(bw2 + (nt*16 + l15)*192 + k0 + q8), a2[nt]);
    }
    const int mb = m0 + wid*16 + q4;                // 4-aligned, never straddles 180
    const int y = mb / 180, hp = mb - y*180;
    #pragma unroll
    for (int nt=0; nt<12; ++nt){
        int n = nt*16 + l15;
        int o = n >> 1, sp = n & 1;
        float bv = b2[(kb*96 + o)*2 + sp];
        v4f vv;
        #pragma unroll
        for (int r=0;r<4;++r) vv[r] = sshrink(a2[nt][r] + bv);
        *(uint2*)(F3 + ((kb*96 + o)*96 + y)*360 + sp*180 + hp) = pk4(vv);
    }
}

// ---------------------------------------------------------------------------
__global__ __launch_bounds__(512) void gHi(const short* __restrict__ F3,
                                           short* __restrict__ Sp,
                                           const short* __restrict__ BHI){
    const int c = blockIdx.x;
    const int tid = threadIdx.x, wid = tid >> 6, lane = tid & 63;
    const int l15 = lane & 15, q8 = (lane >> 4) << 3, q4 = q8 >> 1;
    const int nt0 = wid*3;
    const v4f vz = {0.f,0.f,0.f,0.f};
    v4f acc[6][3];
    #pragma unroll
    for (int i=0;i<6;++i){ acc[i][0]=vz; acc[i][1]=vz; acc[i][2]=vz; }
    for (int ks=0; ks<12; ++ks){
        const int k0 = ks*32;
        int kk = k0 + q8; if (kk >= 360) kk = 0;
        v8s af[6];
        #pragma unroll
        for (int i=0;i<6;++i)
            af[i] = ld8(F3 + (c*96 + i*16 + l15)*360 + kk);
        v8s bf[3];
        #pragma unroll
        for (int j=0;j<3;++j)
            bf[j] = ld8(BHI + ((nt0+j)*16 + l15)*384 + k0 + q8);
        #pragma unroll
        for (int i=0;i<6;++i)
            #pragma unroll
            for (int j=0;j<3;++j)
                acc[i][j] = MFMA(af[i], bf[j], acc[i][j]);
    }
    #pragma unroll
    for (int j=0;j<3;++j){
        int n = (nt0+j)*16 + l15;
        int s = n >= 192, h = n - s*192;
        if (h >= 180) continue;
        const int rb = (c*180 + h)*192 + s*96;
        #pragma unroll
        for (int i=0;i<6;++i)
            *(uint2*)(Sp + rb + i*16 + q4) = pk4(acc[i][j]);
    }
}

// ---------------------------------------------------------------------------
// gE, role-swapped: A = BE rows (m = w), B = Spec rows (n = out row).
// Lane holds D[w0+q4+r][row0+l15] -> 4 consecutive w -> float4 epilogue.
// 8 waves/block: (wid>>1) picks one of 4 row-tiles, (wid&1) picks w-half
// (12 tiles each; global tile 23 reads BE's baked-zero rows 368..383 and
// is skipped by the w<360 store guard). acc = 48 regs -> 4 waves/SIMD.
__global__ __launch_bounds__(512, 4) void gE(const float* __restrict__ x,
                                             const short* __restrict__ Sp,
                                             const short* __restrict__ BE,
                                             float* __restrict__ out){
    const int b = blockIdx.x;
    const int tid = threadIdx.x, wid = tid >> 6, lane = tid & 63;
    const int l15 = lane & 15, q8 = (lane >> 4) << 3, q4 = q8 >> 1;
    const int row = b*64 + (wid >> 1)*16;
    const int t0  = (wid & 1)*12;                   // w-tile base: 0 or 12
    const v4f vz = {0.f,0.f,0.f,0.f};
    v4f acc[12];
    #pragma unroll
    for (int nt=0; nt<12; ++nt) acc[nt]=vz;
    const short* br = Sp + (row + l15)*192;         // B-role: Spec row per lane
    const short* be = BE + (t0*16 + l15)*192;       // A-role: BE row (w) per lane
    for (int ks=0; ks<6; ++ks){
        const int k0 = ks*32 + q8;
        v8s bf = ld8(br + k0);
        #pragma unroll
        for (int nt=0; nt<12; ++nt)
            acc[nt] = MFMA(ld8(be + nt*3072 + k0), bf, acc[nt]);
    }
    const int rbase = (row + l15)*360;
    #pragma unroll
    for (int nt=0; nt<12; ++nt){
        const int w0 = (t0 + nt)*16 + q4;
        if (w0 < 360){
            float4 xv = *(const float4*)(x + rbase + w0);
            float4 ov = make_float4(xv.x + acc[nt][0], xv.y + acc[nt][1],
                                    xv.z + acc[nt][2], xv.w + acc[nt][3]);
            *(float4*)(out + rbase + w0) = ov;
        }
    }
}

// ---------------------------------------------------------------------------
extern "C" void kernel_launch(void* const* d_in, const int* in_sizes, int n_in,
                              void* d_out, int out_size, void* d_ws, size_t ws_size,
                              hipStream_t stream){
    const float* x  = (const float*)d_in[0];
    const float* w1 = (const float*)d_in[1];
    const float* b1 = (const float*)d_in[2];
    const float* w2 = (const float*)d_in[3];
    const float* b2 = (const float*)d_in[4];
    float* out = (float*)d_out;
    short* ws = (short*)d_ws;
    short* B1 = ws;              // G1 then F3 (53.08 MB)
    short* B2 = ws + NBUF;       // F2 then Spec (53.08 MB)

    hipLaunchKernelGGL(bake, dim3((NBAKE+255)/256), dim3(256), 0, stream, w1, w2, ws);
    hipLaunchKernelGGL(gA,  dim3(1536),    dim3(256), 0, stream, x, B1, ws + OBA);
    hipLaunchKernelGGL(gHf, dim3(768),     dim3(512), 0, stream, B1, B2, ws + OBH);
    hipLaunchKernelGGL(gC,  dim3(270, 8),  dim3(256), 0, stream, B2, B1,
                       ws + OBW1, ws + OBW2, b1, b2);
    hipLaunchKernelGGL(gHi, dim3(768),     dim3(512), 0, stream, B1, B2, ws + OBHI);
    hipLaunchKernelGGL(gE,  dim3(2160),    dim3(512), 0, stream, x, B2, ws + OBE, out);
}

// Round 2
// 943.037 us; speedup vs baseline: 1.0452x; 1.0452x over previous
//
#include <hip/hip_runtime.h>
#include <math.h>

// ---------------------------------------------------------------------------
// AFNO2D as 5 bf16-MFMA GEMM stages + constant bake.
//   x:[1,768,180,360] f32. rfft2(ortho) -> per-mode blockdiag complex MLP
//   (8 blocks x 96ch, relu, softshrink, W-modes y<91 kept) -> irfft2 + x.
//
// GEMM forms (D = A*B, mfma_f32_16x16x32_bf16):
//  gA : per (c, h-half): D[m=h(96)][n=(s*96+y)(192)] = x-rows(K=384) * BA
//       store transposed -> G1[c][y][s*180+h]        (regs = 4 consecutive h)
//  gHf: per c: D[m=(s*192+h')(384)][n=y(96)] = BH(A) * G1-rows(B, K=384)
//       store -> F2[c2=2c+s][y*180+h']               (regs = 4 consecutive h')
//  gC : per (kb, 64-mode tile): Act(LDS-transposed from F2) * BW1 -> relu
//       -> *BW2 -> softshrink, store -> F3[cout][y][s'*180+h'] (4 consec h')
//  gHi: per c: D[m=y(96)][n=(s*192+h)(384)] = F3-rows(A) * BHI(B)
//       store -> Spec[(c*180+h)][s*96+y]             (regs = 4 consecutive y)
//  gE : per 64-row tile, ROLE-SWAPPED: D[m=w(384)][n=row(64)] =
//       BE-rows(A) * Spec-rows(B, K=192), C-INIT = x (residual folded into
//       the MFMA accumulator; x loads issue first and overlap the GEMM).
//       Epilogue is store-only float4. 8 waves/block.
// Fragment layouts used (guide-verified): A[m=l&15][k=q*8+j],
// B[k=q*8+j][n=l&15], C/D[row=q*4+reg][col=l&15].
// ---------------------------------------------------------------------------

#define R360f 0.05270462766947299f   // 1/sqrt(360)
#define R180f 0.07453559924999299f   // 1/sqrt(180)
#define LAM   0.01f

typedef short v8s __attribute__((ext_vector_type(8)));
typedef float v4f __attribute__((ext_vector_type(4)));

#define MFMA(a,b,c) __builtin_amdgcn_mfma_f32_16x16x32_bf16(a,b,c,0,0,0)

// ws layout (shorts): BUF1 | BUF2 | BA | BH | BHI | BW1 | BW2 | BE
#define NBUF  26542080              // 53,084,160 B per ping-pong buffer
#define OBA   (2*NBUF)
#define OBH   (OBA + 73728)         // BA  [192][384]
#define OBHI  (OBH + 147456)        // BH  [384][384]
#define OBW1  (OBHI + 147456)       // BHI [384][384]
#define OBW2  (OBW1 + 294912)       // BW1 [8][192][192]
#define OBE   (OBW2 + 294912)       // BW2 [8][192][192]
#define NBAKE 1032192               // + BE [384][192]

static __device__ __forceinline__ short f2bs(float f){   // f32 -> bf16 (RNE)
    unsigned u = __builtin_bit_cast(unsigned, f);
    u = (u + 0x7fffu + ((u >> 16) & 1u)) >> 16;
    return (short)u;
}
static __device__ __forceinline__ v8s ld8(const short* p){
    return __builtin_bit_cast(v8s, *(const uint4*)p);
}
union PK { short s[4]; uint2 u; };
static __device__ __forceinline__ uint2 pk4(v4f a){
    PK t; t.s[0]=f2bs(a[0]); t.s[1]=f2bs(a[1]); t.s[2]=f2bs(a[2]); t.s[3]=f2bs(a[3]);
    return t.u;
}
union S8 { uint4 u; short s[8]; v8s v; };
static __device__ __forceinline__ float sshrink(float v){
    return (v > LAM) ? (v - LAM) : ((v < -LAM) ? (v + LAM) : 0.f);
}

// ---------------------------------------------------------------------------
__global__ __launch_bounds__(256) void bake(const float* __restrict__ w1,
                                            const float* __restrict__ w2,
                                            short* __restrict__ bt){
    int idx = blockIdx.x*256 + threadIdx.x;
    if (idx >= NBAKE) return;
    float v = 0.f;
    if (idx < 73728){                               // BA (B-role) [n=s*96+y][k=w]
        int n = idx/384, k = idx - n*384;
        int s = n >= 96, y = n - s*96;
        if (y < 91 && k < 360){
            float th = (float)((k*y) % 360) * 0.017453292519943295f;
            float sv, cv; sincosf(th, &sv, &cv);
            v = s ? -sv*R360f : cv*R360f;           // e^{-i th}
        }
        bt[OBA + idx] = f2bs(v); return;
    }
    idx -= 73728;
    if (idx < 147456){                              // BH (A-role) [m=s*192+h'][k=si*180+h]
        int m = idx/384, k = idx - m*384;
        int s = m >= 192, hp = m - s*192;
        if (hp < 180 && k < 360){
            int si = k >= 180; int h = k - si*180;
            float th = (float)((h*hp) % 180) * 0.03490658503988659f;
            float sv, cv; sincosf(th, &sv, &cv);
            v = R180f * (s == 0 ? (si == 0 ? cv : sv) : (si == 0 ? -sv : cv));
        }
        bt[OBH + idx] = f2bs(v); return;
    }
    idx -= 147456;
    if (idx < 147456){                              // BHI (B-role) [n=s*192+h][k=sp*180+h']
        int n = idx/384, k = idx - n*384;
        int s = n >= 192, h = n - s*192;
        if (h < 180 && k < 360){
            int sp = k >= 180; int hp = k - sp*180;
            float th = (float)((h*hp) % 180) * 0.03490658503988659f;
            float sv, cv; sincosf(th, &sv, &cv);
            v = R180f * (s == 0 ? (sp == 0 ? cv : -sv) : (sp == 0 ? sv : cv));
        }
        bt[OBHI + idx] = f2bs(v); return;
    }
    idx -= 147456;
    if (idx < 294912){                              // BW1 (B-role) [kb][n=2o+sp][k=2i+si]
        int kb = idx / 36864; int r = idx - kb*36864;
        int n = r / 192, k = r - n*192;
        int o = n >> 1, sp = n & 1, i = k >> 1, si = k & 1;
        const float* wp = w1 + ((((kb*96 + i)*96) + o) << 1);
        v = sp == 0 ? (si == 0 ? wp[0] : -wp[1]) : (si == 0 ? wp[1] : wp[0]);
        bt[OBW1 + idx] = f2bs(v); return;
    }
    idx -= 294912;
    if (idx < 294912){                              // BW2
        int kb = idx / 36864; int r = idx - kb*36864;
        int n = r / 192, k = r - n*192;
        int o = n >> 1, sp = n & 1, i = k >> 1, si = k & 1;
        const float* wp = w2 + ((((kb*96 + i)*96) + o) << 1);
        v = sp == 0 ? (si == 0 ? wp[0] : -wp[1]) : (si == 0 ? wp[1] : wp[0]);
        bt[OBW2 + idx] = f2bs(v); return;
    }
    idx -= 294912;
    {                                               // BE [w(384)][k=s*96+y]
        int w = idx / 192, k = idx - w*192;
        int s = k >= 96, y = k - s*96;
        if (w < 360 && y < 91){
            float th = (float)((y*w) % 360) * 0.017453292519943295f;
            float sv, cv; sincosf(th, &sv, &cv);
            v = (s == 0) ? (y == 0 ? 1.f : 2.f) * cv * R360f
                         : (y == 0 ? 0.f : -2.f*sv*R360f);
        }
        bt[OBE + idx] = f2bs(v);
    }
}

// ---------------------------------------------------------------------------
__global__ __launch_bounds__(256) void gA(const float* __restrict__ x,
                                          short* __restrict__ G1,
                                          const short* __restrict__ BA){
    const int b = blockIdx.x, c = b >> 1, hh = (b & 1)*96;
    const int tid = threadIdx.x, wid = tid >> 6, lane = tid & 63;
    const int l15 = lane & 15, q8 = (lane >> 4) << 3, q4 = q8 >> 1;
    const int nt0 = wid*3;
    const v4f vz = {0.f,0.f,0.f,0.f};
    v4f acc[6][3];
    #pragma unroll
    for (int i=0;i<6;++i){ acc[i][0]=vz; acc[i][1]=vz; acc[i][2]=vz; }
    for (int ks=0; ks<12; ++ks){
        const int k0 = ks*32;
        int kk = k0 + q8; if (kk >= 360) kk = 0;   // garbage * zero B-rows
        v8s af[6];
        #pragma unroll
        for (int mt=0; mt<6; ++mt){
            int h = hh + mt*16 + l15; if (h > 179) h = 179;  // rows>=180 dropped at store
            const float* xp = x + (c*180 + h)*360 + kk;
            float4 f0 = *(const float4*)xp;
            float4 f1 = *(const float4*)(xp + 4);
            S8 tt;
            tt.s[0]=f2bs(f0.x); tt.s[1]=f2bs(f0.y); tt.s[2]=f2bs(f0.z); tt.s[3]=f2bs(f0.w);
            tt.s[4]=f2bs(f1.x); tt.s[5]=f2bs(f1.y); tt.s[6]=f2bs(f1.z); tt.s[7]=f2bs(f1.w);
            af[mt] = tt.v;
        }
        v8s bf[3];
        #pragma unroll
        for (int j=0;j<3;++j)
            bf[j] = ld8(BA + ((nt0+j)*16 + l15)*384 + k0 + q8);
        #pragma unroll
        for (int mt=0; mt<6; ++mt)
            #pragma unroll
            for (int j=0;j<3;++j)
                acc[mt][j] = MFMA(af[mt], bf[j], acc[mt][j]);
    }
    #pragma unroll
    for (int mt=0; mt<6; ++mt){
        int hg = hh + mt*16 + q4;                   // 4-aligned, never straddles 180
        if (hg >= 180) continue;
        #pragma unroll
        for (int j=0;j<3;++j){
            int n = (nt0+j)*16 + l15;
            int s = n >= 96, y = n - s*96;
            *(uint2*)(G1 + (c*96 + y)*360 + s*180 + hg) = pk4(acc[mt][j]);
        }
    }
}

// ---------------------------------------------------------------------------
__global__ __launch_bounds__(512) void gHf(const short* __restrict__ G1,
                                           short* __restrict__ F2,
                                           const short* __restrict__ BH){
    const int c = blockIdx.x;
    const int tid = threadIdx.x, wid = tid >> 6, lane = tid & 63;
    const int l15 = lane & 15, q8 = (lane >> 4) << 3, q4 = q8 >> 1;
    const int mt0 = wid*3;
    const v4f vz = {0.f,0.f,0.f,0.f};
    v4f acc[3][6];
    #pragma unroll
    for (int i=0;i<3;++i)
        #pragma unroll
        for (int j=0;j<6;++j) acc[i][j]=vz;
    for (int ks=0; ks<12; ++ks){
        const int k0 = ks*32;
        int kk = k0 + q8; if (kk >= 360) kk = 0;
        v8s af[3];
        #pragma unroll
        for (int i=0;i<3;++i)
            af[i] = ld8(BH + ((mt0+i)*16 + l15)*384 + k0 + q8);
        v8s bf[6];
        #pragma unroll
        for (int j=0;j<6;++j)
            bf[j] = ld8(G1 + (c*96 + j*16 + l15)*360 + kk);
        #pragma unroll
        for (int i=0;i<3;++i)
            #pragma unroll
            for (int j=0;j<6;++j)
                acc[i][j] = MFMA(af[i], bf[j], acc[i][j]);
    }
    #pragma unroll
    for (int i=0;i<3;++i){
        int m = (mt0+i)*16 + q4;
        int s = m >= 192, hp = m - s*192;
        if (hp >= 180) continue;
        const int rb = (2*c + s)*17280 + hp;
        #pragma unroll
        for (int j=0;j<6;++j){
            int y = j*16 + l15;
            *(uint2*)(F2 + rb + y*180) = pk4(acc[i][j]);
        }
    }
}

// ---------------------------------------------------------------------------
__global__ __launch_bounds__(256) void gC(const short* __restrict__ F2,
                                          short* __restrict__ F3,
                                          const short* __restrict__ BW1,
                                          const short* __restrict__ BW2,
                                          const float* __restrict__ b1,
                                          const float* __restrict__ b2){
    __shared__ short Act[64*200];    // [mode 64][ch2 192 + 8 pad]
    __shared__ short O1[64*200];
    const int mt = blockIdx.x, kb = blockIdx.y, m0 = mt*64;
    const int tid = threadIdx.x;
    #pragma unroll
    for (int i=0;i<6;++i){           // 1536 16B-chunks: transpose F2 -> Act
        int ch = tid + 256*i;
        int qq = ch / 192, rr = ch - qq*192;
        S8 tt; tt.u = *(const uint4*)(F2 + (kb*192 + rr)*17280 + m0 + qq*8);
        #pragma unroll
        for (int j=0;j<8;++j) Act[(qq*8+j)*200 + rr] = tt.s[j];  // consec lanes -> consec elems
    }
    __syncthreads();
    const int wid = tid >> 6, lane = tid & 63, l15 = lane & 15;
    const int q8 = (lane >> 4) << 3, q4 = q8 >> 1;
    const short* bw1 = BW1 + kb*36864;
    const short* bw2 = BW2 + kb*36864;
    const v4f vz = {0.f,0.f,0.f,0.f};
    v4f a1[12];
    #pragma unroll
    for (int nt=0; nt<12; ++nt) a1[nt]=vz;
    for (int ks=0; ks<6; ++ks){
        int k0 = ks*32;
        v8s af = __builtin_bit_cast(v8s, *(const uint4*)(Act + (wid*16 + l15)*200 + k0 + q8));
        #pragma unroll
        for (int nt=0; nt<12; ++nt)
            a1[nt] = MFMA(af, ld8(bw1 + (nt*16 + l15)*192 + k0 + q8), a1[nt]);
    }
    #pragma unroll
    for (int nt=0; nt<12; ++nt){
        int n = nt*16 + l15;
        float bv = b1[(kb*96 + (n>>1))*2 + (n&1)];
        #pragma unroll
        for (int r=0;r<4;++r)
            O1[(wid*16 + q4 + r)*200 + n] = f2bs(fmaxf(a1[nt][r] + bv, 0.f));
    }
    // wave w wrote exactly rows [w*16, w*16+16) and reads only those: no barrier.
    v4f a2[12];
    #pragma unroll
    for (int nt=0; nt<12; ++nt) a2[nt]=vz;
    for (int ks=0; ks<6; ++ks){
        int k0 = ks*32;
        v8s af = __builtin_bit_cast(v8s, *(const uint4*)(O1 + (wid*16 + l15)*200 + k0 + q8));
        #pragma unroll
        for (int nt=0; nt<12; ++nt)
            a2[nt] = MFMA(af, ld8(bw2 + (nt*16 + l15)*192 + k0 + q8), a2[nt]);
    }
    const int mb = m0 + wid*16 + q4;                // 4-aligned, never straddles 180
    const int y = mb / 180, hp = mb - y*180;
    #pragma unroll
    for (int nt=0; nt<12; ++nt){
        int n = nt*16 + l15;
        int o = n >> 1, sp = n & 1;
        float bv = b2[(kb*96 + o)*2 + sp];
        v4f vv;
        #pragma unroll
        for (int r=0;r<4;++r) vv[r] = sshrink(a2[nt][r] + bv);
        *(uint2*)(F3 + ((kb*96 + o)*96 + y)*360 + sp*180 + hp) = pk4(vv);
    }
}

// ---------------------------------------------------------------------------
__global__ __launch_bounds__(512) void gHi(const short* __restrict__ F3,
                                           short* __restrict__ Sp,
                                           const short* __restrict__ BHI){
    const int c = blockIdx.x;
    const int tid = threadIdx.x, wid = tid >> 6, lane = tid & 63;
    const int l15 = lane & 15, q8 = (lane >> 4) << 3, q4 = q8 >> 1;
    const int nt0 = wid*3;
    const v4f vz = {0.f,0.f,0.f,0.f};
    v4f acc[6][3];
    #pragma unroll
    for (int i=0;i<6;++i){ acc[i][0]=vz; acc[i][1]=vz; acc[i][2]=vz; }
    for (int ks=0; ks<12; ++ks){
        const int k0 = ks*32;
        int kk = k0 + q8; if (kk >= 360) kk = 0;
        v8s af[6];
        #pragma unroll
        for (int i=0;i<6;++i)
            af[i] = ld8(F3 + (c*96 + i*16 + l15)*360 + kk);
        v8s bf[3];
        #pragma unroll
        for (int j=0;j<3;++j)
            bf[j] = ld8(BHI + ((nt0+j)*16 + l15)*384 + k0 + q8);
        #pragma unroll
        for (int i=0;i<6;++i)
            #pragma unroll
            for (int j=0;j<3;++j)
                acc[i][j] = MFMA(af[i], bf[j], acc[i][j]);
    }
    #pragma unroll
    for (int j=0;j<3;++j){
        int n = (nt0+j)*16 + l15;
        int s = n >= 192, h = n - s*192;
        if (h >= 180) continue;
        const int rb = (c*180 + h)*192 + s*96;
        #pragma unroll
        for (int i=0;i<6;++i)
            *(uint2*)(Sp + rb + i*16 + q4) = pk4(acc[i][j]);
    }
}

// ---------------------------------------------------------------------------
// gE, role-swapped + residual folded into the accumulator:
//   A = BE rows (m = w), B = Spec rows (n = out row), C-init = x.
// The 12 guarded float4 x-loads issue FIRST and overlap the whole GEMM
// main loop (MFMA C-input = x means out = x + irfft directly); epilogue is
// store-only so no wave ever stalls on an x round-trip after compute.
// 8 waves/block: (wid>>1) = row-tile, (wid&1) = w-half (12 tiles each;
// w>=360 tiles read BE's baked-zero rows and are init-0 / store-guarded).
__global__ __launch_bounds__(512, 4) void gE(const float* __restrict__ x,
                                             const short* __restrict__ Sp,
                                             const short* __restrict__ BE,
                                             float* __restrict__ out){
    const int b = blockIdx.x;
    const int tid = threadIdx.x, wid = tid >> 6, lane = tid & 63;
    const int l15 = lane & 15, q8 = (lane >> 4) << 3, q4 = q8 >> 1;
    const int row = b*64 + (wid >> 1)*16;
    const int t0  = (wid & 1)*12;                   // w-tile base: 0 or 12
    const int rbase = (row + l15)*360;
    v4f acc[12];
    #pragma unroll
    for (int nt=0; nt<12; ++nt){                    // C-init = x (overlaps GEMM)
        const int w0 = (t0 + nt)*16 + q4;
        if (w0 < 360){
            float4 xv = *(const float4*)(x + rbase + w0);
            acc[nt][0]=xv.x; acc[nt][1]=xv.y; acc[nt][2]=xv.z; acc[nt][3]=xv.w;
        } else {
            acc[nt] = (v4f){0.f,0.f,0.f,0.f};
        }
    }
    const short* br = Sp + (row + l15)*192;         // B-role: Spec row per lane
    const short* be = BE + (t0*16 + l15)*192;       // A-role: BE row (w) per lane
    for (int ks=0; ks<6; ++ks){
        const int k0 = ks*32 + q8;
        v8s bf = ld8(br + k0);
        #pragma unroll
        for (int nt=0; nt<12; ++nt)
            acc[nt] = MFMA(ld8(be + nt*3072 + k0), bf, acc[nt]);
    }
    #pragma unroll
    for (int nt=0; nt<12; ++nt){                    // store-only epilogue
        const int w0 = (t0 + nt)*16 + q4;
        if (w0 < 360)
            *(float4*)(out + rbase + w0) =
                make_float4(acc[nt][0], acc[nt][1], acc[nt][2], acc[nt][3]);
    }
}

// ---------------------------------------------------------------------------
extern "C" void kernel_launch(void* const* d_in, const int* in_sizes, int n_in,
                              void* d_out, int out_size, void* d_ws, size_t ws_size,
                              hipStream_t stream){
    const float* x  = (const float*)d_in[0];
    const float* w1 = (const float*)d_in[1];
    const float* b1 = (const float*)d_in[2];
    const float* w2 = (const float*)d_in[3];
    const float* b2 = (const float*)d_in[4];
    float* out = (float*)d_out;
    short* ws = (short*)d_ws;
    short* B1 = ws;              // G1 then F3 (53.08 MB)
    short* B2 = ws + NBUF;       // F2 then Spec (53.08 MB)

    hipLaunchKernelGGL(bake, dim3((NBAKE+255)/256), dim3(256), 0, stream, w1, w2, ws);
    hipLaunchKernelGGL(gA,  dim3(1536),    dim3(256), 0, stream, x, B1, ws + OBA);
    hipLaunchKernelGGL(gHf, dim3(768),     dim3(512), 0, stream, B1, B2, ws + OBH);
    hipLaunchKernelGGL(gC,  dim3(270, 8),  dim3(256), 0, stream, B2, B1,
                       ws + OBW1, ws + OBW2, b1, b2);
    hipLaunchKernelGGL(gHi, dim3(768),     dim3(512), 0, stream, B1, B2, ws + OBHI);
    hipLaunchKernelGGL(gE,  dim3(2160),    dim3(512), 0, stream, x, B2, ws + OBE, out);
}

// Round 3
// 866.325 us; speedup vs baseline: 1.1378x; 1.0885x over previous
//
#include <hip/hip_runtime.h>
#include <math.h>

// ---------------------------------------------------------------------------
// AFNO2D as 5 bf16-MFMA GEMM stages + constant bake.
//   x:[1,768,180,360] f32. rfft2(ortho) -> per-mode blockdiag complex MLP
//   (8 blocks x 96ch, relu, softshrink, W-modes y<91 kept) -> irfft2 + x.
//
// GEMM forms (D = A*B, mfma_f32_16x16x32_bf16):
//  gA : per (c, h-half): D[m=h(96)][n=(s*96+y)(192)] = x-rows(K=384) * BA
//       store transposed -> G1[c][y][s*180+h]        (regs = 4 consecutive h)
//  gHf: per c: D[m=(s*192+h')(384)][n=y(96)] = BH(A) * G1-rows(B, K=384)
//       store -> F2[c2=2c+s][y*180+h']               (regs = 4 consecutive h')
//  gC : per (kb, 64-mode tile): Act(LDS-transposed from F2) * BW1 -> relu
//       -> *BW2 -> softshrink, store -> F3[cout][y][s'*180+h'] (4 consec h')
//  gHi: per c: D[m=y(96)][n=(s*192+h)(384)] = F3-rows(A) * BHI(B)
//       store -> Spec[(c*180+h)][s*96+y]             (regs = 4 consecutive y)
//  gE : ROLE-SWAPPED + 2-D wave tile: block = 8 waves = 128 rows x 360 w.
//       Wave = 64 rows (4 n-subtiles) x 96 w (6 m-tiles, one w-quarter).
//       D[m=w][n=row] = BE-rows(A) * Spec-rows(B, K=192), C-init = x.
//       Per ks: 10 loads (6 BE + 4 Spec, L2-resident) feed 24 MFMAs --
//       2.6x fewer loads/MFMA than the 1-D tile, so the wave returns to
//       the HBM stream (x loads / stores) sooner. Store-only epilogue.
// Fragment layouts used (guide-verified): A[m=l&15][k=q*8+j],
// B[k=q*8+j][n=l&15], C/D[row=q*4+reg][col=l&15].
// ---------------------------------------------------------------------------

#define R360f 0.05270462766947299f   // 1/sqrt(360)
#define R180f 0.07453559924999299f   // 1/sqrt(180)
#define LAM   0.01f

typedef short v8s __attribute__((ext_vector_type(8)));
typedef float v4f __attribute__((ext_vector_type(4)));

#define MFMA(a,b,c) __builtin_amdgcn_mfma_f32_16x16x32_bf16(a,b,c,0,0,0)

// ws layout (shorts): BUF1 | BUF2 | BA | BH | BHI | BW1 | BW2 | BE
#define NBUF  26542080              // 53,084,160 B per ping-pong buffer
#define OBA   (2*NBUF)
#define OBH   (OBA + 73728)         // BA  [192][384]
#define OBHI  (OBH + 147456)        // BH  [384][384]
#define OBW1  (OBHI + 147456)       // BHI [384][384]
#define OBW2  (OBW1 + 294912)       // BW1 [8][192][192]
#define OBE   (OBW2 + 294912)       // BW2 [8][192][192]
#define NBAKE 1032192               // + BE [384][192]

static __device__ __forceinline__ short f2bs(float f){   // f32 -> bf16 (RNE)
    unsigned u = __builtin_bit_cast(unsigned, f);
    u = (u + 0x7fffu + ((u >> 16) & 1u)) >> 16;
    return (short)u;
}
static __device__ __forceinline__ v8s ld8(const short* p){
    return __builtin_bit_cast(v8s, *(const uint4*)p);
}
union PK { short s[4]; uint2 u; };
static __device__ __forceinline__ uint2 pk4(v4f a){
    PK t; t.s[0]=f2bs(a[0]); t.s[1]=f2bs(a[1]); t.s[2]=f2bs(a[2]); t.s[3]=f2bs(a[3]);
    return t.u;
}
union S8 { uint4 u; short s[8]; v8s v; };
static __device__ __forceinline__ float sshrink(float v){
    return (v > LAM) ? (v - LAM) : ((v < -LAM) ? (v + LAM) : 0.f);
}

// ---------------------------------------------------------------------------
__global__ __launch_bounds__(256) void bake(const float* __restrict__ w1,
                                            const float* __restrict__ w2,
                                            short* __restrict__ bt){
    int idx = blockIdx.x*256 + threadIdx.x;
    if (idx >= NBAKE) return;
    float v = 0.f;
    if (idx < 73728){                               // BA (B-role) [n=s*96+y][k=w]
        int n = idx/384, k = idx - n*384;
        int s = n >= 96, y = n - s*96;
        if (y < 91 && k < 360){
            float th = (float)((k*y) % 360) * 0.017453292519943295f;
            float sv, cv; sincosf(th, &sv, &cv);
            v = s ? -sv*R360f : cv*R360f;           // e^{-i th}
        }
        bt[OBA + idx] = f2bs(v); return;
    }
    idx -= 73728;
    if (idx < 147456){                              // BH (A-role) [m=s*192+h'][k=si*180+h]
        int m = idx/384, k = idx - m*384;
        int s = m >= 192, hp = m - s*192;
        if (hp < 180 && k < 360){
            int si = k >= 180; int h = k - si*180;
            float th = (float)((h*hp) % 180) * 0.03490658503988659f;
            float sv, cv; sincosf(th, &sv, &cv);
            v = R180f * (s == 0 ? (si == 0 ? cv : sv) : (si == 0 ? -sv : cv));
        }
        bt[OBH + idx] = f2bs(v); return;
    }
    idx -= 147456;
    if (idx < 147456){                              // BHI (B-role) [n=s*192+h][k=sp*180+h']
        int n = idx/384, k = idx - n*384;
        int s = n >= 192, h = n - s*192;
        if (h < 180 && k < 360){
            int sp = k >= 180; int hp = k - sp*180;
            float th = (float)((h*hp) % 180) * 0.03490658503988659f;
            float sv, cv; sincosf(th, &sv, &cv);
            v = R180f * (s == 0 ? (sp == 0 ? cv : -sv) : (sp == 0 ? sv : cv));
        }
        bt[OBHI + idx] = f2bs(v); return;
    }
    idx -= 147456;
    if (idx < 294912){                              // BW1 (B-role) [kb][n=2o+sp][k=2i+si]
        int kb = idx / 36864; int r = idx - kb*36864;
        int n = r / 192, k = r - n*192;
        int o = n >> 1, sp = n & 1, i = k >> 1, si = k & 1;
        const float* wp = w1 + ((((kb*96 + i)*96) + o) << 1);
        v = sp == 0 ? (si == 0 ? wp[0] : -wp[1]) : (si == 0 ? wp[1] : wp[0]);
        bt[OBW1 + idx] = f2bs(v); return;
    }
    idx -= 294912;
    if (idx < 294912){                              // BW2
        int kb = idx / 36864; int r = idx - kb*36864;
        int n = r / 192, k = r - n*192;
        int o = n >> 1, sp = n & 1, i = k >> 1, si = k & 1;
        const float* wp = w2 + ((((kb*96 + i)*96) + o) << 1);
        v = sp == 0 ? (si == 0 ? wp[0] : -wp[1]) : (si == 0 ? wp[1] : wp[0]);
        bt[OBW2 + idx] = f2bs(v); return;
    }
    idx -= 294912;
    {                                               // BE [w(384)][k=s*96+y]
        int w = idx / 192, k = idx - w*192;
        int s = k >= 96, y = k - s*96;
        if (w < 360 && y < 91){
            float th = (float)((y*w) % 360) * 0.017453292519943295f;
            float sv, cv; sincosf(th, &sv, &cv);
            v = (s == 0) ? (y == 0 ? 1.f : 2.f) * cv * R360f
                         : (y == 0 ? 0.f : -2.f*sv*R360f);
        }
        bt[OBE + idx] = f2bs(v);
    }
}

// ---------------------------------------------------------------------------
__global__ __launch_bounds__(256) void gA(const float* __restrict__ x,
                                          short* __restrict__ G1,
                                          const short* __restrict__ BA){
    const int b = blockIdx.x, c = b >> 1, hh = (b & 1)*96;
    const int tid = threadIdx.x, wid = tid >> 6, lane = tid & 63;
    const int l15 = lane & 15, q8 = (lane >> 4) << 3, q4 = q8 >> 1;
    const int nt0 = wid*3;
    const v4f vz = {0.f,0.f,0.f,0.f};
    v4f acc[6][3];
    #pragma unroll
    for (int i=0;i<6;++i){ acc[i][0]=vz; acc[i][1]=vz; acc[i][2]=vz; }
    for (int ks=0; ks<12; ++ks){
        const int k0 = ks*32;
        int kk = k0 + q8; if (kk >= 360) kk = 0;   // garbage * zero B-rows
        v8s af[6];
        #pragma unroll
        for (int mt=0; mt<6; ++mt){
            int h = hh + mt*16 + l15; if (h > 179) h = 179;  // rows>=180 dropped at store
            const float* xp = x + (c*180 + h)*360 + kk;
            float4 f0 = *(const float4*)xp;
            float4 f1 = *(const float4*)(xp + 4);
            S8 tt;
            tt.s[0]=f2bs(f0.x); tt.s[1]=f2bs(f0.y); tt.s[2]=f2bs(f0.z); tt.s[3]=f2bs(f0.w);
            tt.s[4]=f2bs(f1.x); tt.s[5]=f2bs(f1.y); tt.s[6]=f2bs(f1.z); tt.s[7]=f2bs(f1.w);
            af[mt] = tt.v;
        }
        v8s bf[3];
        #pragma unroll
        for (int j=0;j<3;++j)
            bf[j] = ld8(BA + ((nt0+j)*16 + l15)*384 + k0 + q8);
        #pragma unroll
        for (int mt=0; mt<6; ++mt)
            #pragma unroll
            for (int j=0;j<3;++j)
                acc[mt][j] = MFMA(af[mt], bf[j], acc[mt][j]);
    }
    #pragma unroll
    for (int mt=0; mt<6; ++mt){
        int hg = hh + mt*16 + q4;                   // 4-aligned, never straddles 180
        if (hg >= 180) continue;
        #pragma unroll
        for (int j=0;j<3;++j){
            int n = (nt0+j)*16 + l15;
            int s = n >= 96, y = n - s*96;
            *(uint2*)(G1 + (c*96 + y)*360 + s*180 + hg) = pk4(acc[mt][j]);
        }
    }
}

// ---------------------------------------------------------------------------
__global__ __launch_bounds__(512) void gHf(const short* __restrict__ G1,
                                           short* __restrict__ F2,
                                           const short* __restrict__ BH){
    const int c = blockIdx.x;
    const int tid = threadIdx.x, wid = tid >> 6, lane = tid & 63;
    const int l15 = lane & 15, q8 = (lane >> 4) << 3, q4 = q8 >> 1;
    const int mt0 = wid*3;
    const v4f vz = {0.f,0.f,0.f,0.f};
    v4f acc[3][6];
    #pragma unroll
    for (int i=0;i<3;++i)
        #pragma unroll
        for (int j=0;j<6;++j) acc[i][j]=vz;
    for (int ks=0; ks<12; ++ks){
        const int k0 = ks*32;
        int kk = k0 + q8; if (kk >= 360) kk = 0;
        v8s af[3];
        #pragma unroll
        for (int i=0;i<3;++i)
            af[i] = ld8(BH + ((mt0+i)*16 + l15)*384 + k0 + q8);
        v8s bf[6];
        #pragma unroll
        for (int j=0;j<6;++j)
            bf[j] = ld8(G1 + (c*96 + j*16 + l15)*360 + kk);
        #pragma unroll
        for (int i=0;i<3;++i)
            #pragma unroll
            for (int j=0;j<6;++j)
                acc[i][j] = MFMA(af[i], bf[j], acc[i][j]);
    }
    #pragma unroll
    for (int i=0;i<3;++i){
        int m = (mt0+i)*16 + q4;
        int s = m >= 192, hp = m - s*192;
        if (hp >= 180) continue;
        const int rb = (2*c + s)*17280 + hp;
        #pragma unroll
        for (int j=0;j<6;++j){
            int y = j*16 + l15;
            *(uint2*)(F2 + rb + y*180) = pk4(acc[i][j]);
        }
    }
}

// ---------------------------------------------------------------------------
__global__ __launch_bounds__(256) void gC(const short* __restrict__ F2,
                                          short* __restrict__ F3,
                                          const short* __restrict__ BW1,
                                          const short* __restrict__ BW2,
                                          const float* __restrict__ b1,
                                          const float* __restrict__ b2){
    __shared__ short Act[64*200];    // [mode 64][ch2 192 + 8 pad]
    __shared__ short O1[64*200];
    const int mt = blockIdx.x, kb = blockIdx.y, m0 = mt*64;
    const int tid = threadIdx.x;
    #pragma unroll
    for (int i=0;i<6;++i){           // 1536 16B-chunks: transpose F2 -> Act
        int ch = tid + 256*i;
        int qq = ch / 192, rr = ch - qq*192;
        S8 tt; tt.u = *(const uint4*)(F2 + (kb*192 + rr)*17280 + m0 + qq*8);
        #pragma unroll
        for (int j=0;j<8;++j) Act[(qq*8+j)*200 + rr] = tt.s[j];  // consec lanes -> consec elems
    }
    __syncthreads();
    const int wid = tid >> 6, lane = tid & 63, l15 = lane & 15;
    const int q8 = (lane >> 4) << 3, q4 = q8 >> 1;
    const short* bw1 = BW1 + kb*36864;
    const short* bw2 = BW2 + kb*36864;
    const v4f vz = {0.f,0.f,0.f,0.f};
    v4f a1[12];
    #pragma unroll
    for (int nt=0; nt<12; ++nt) a1[nt]=vz;
    for (int ks=0; ks<6; ++ks){
        int k0 = ks*32;
        v8s af = __builtin_bit_cast(v8s, *(const uint4*)(Act + (wid*16 + l15)*200 + k0 + q8));
        #pragma unroll
        for (int nt=0; nt<12; ++nt)
            a1[nt] = MFMA(af, ld8(bw1 + (nt*16 + l15)*192 + k0 + q8), a1[nt]);
    }
    #pragma unroll
    for (int nt=0; nt<12; ++nt){
        int n = nt*16 + l15;
        float bv = b1[(kb*96 + (n>>1))*2 + (n&1)];
        #pragma unroll
        for (int r=0;r<4;++r)
            O1[(wid*16 + q4 + r)*200 + n] = f2bs(fmaxf(a1[nt][r] + bv, 0.f));
    }
    // wave w wrote exactly rows [w*16, w*16+16) and reads only those: no barrier.
    v4f a2[12];
    #pragma unroll
    for (int nt=0; nt<12; ++nt) a2[nt]=vz;
    for (int ks=0; ks<6; ++ks){
        int k0 = ks*32;
        v8s af = __builtin_bit_cast(v8s, *(const uint4*)(O1 + (wid*16 + l15)*200 + k0 + q8));
        #pragma unroll
        for (int nt=0; nt<12; ++nt)
            a2[nt] = MFMA(af, ld8(bw2 + (nt*16 + l15)*192 + k0 + q8), a2[nt]);
    }
    const int mb = m0 + wid*16 + q4;                // 4-aligned, never straddles 180
    const int y = mb / 180, hp = mb - y*180;
    #pragma unroll
    for (int nt=0; nt<12; ++nt){
        int n = nt*16 + l15;
        int o = n >> 1, sp = n & 1;
        float bv = b2[(kb*96 + o)*2 + sp];
        v4f vv;
        #pragma unroll
        for (int r=0;r<4;++r) vv[r] = sshrink(a2[nt][r] + bv);
        *(uint2*)(F3 + ((kb*96 + o)*96 + y)*360 + sp*180 + hp) = pk4(vv);
    }
}

// ---------------------------------------------------------------------------
__global__ __launch_bounds__(512) void gHi(const short* __restrict__ F3,
                                           short* __restrict__ Sp,
                                           const short* __restrict__ BHI){
    const int c = blockIdx.x;
    const int tid = threadIdx.x, wid = tid >> 6, lane = tid & 63;
    const int l15 = lane & 15, q8 = (lane >> 4) << 3, q4 = q8 >> 1;
    const int nt0 = wid*3;
    const v4f vz = {0.f,0.f,0.f,0.f};
    v4f acc[6][3];
    #pragma unroll
    for (int i=0;i<6;++i){ acc[i][0]=vz; acc[i][1]=vz; acc[i][2]=vz; }
    for (int ks=0; ks<12; ++ks){
        const int k0 = ks*32;
        int kk = k0 + q8; if (kk >= 360) kk = 0;
        v8s af[6];
        #pragma unroll
        for (int i=0;i<6;++i)
            af[i] = ld8(F3 + (c*96 + i*16 + l15)*360 + kk);
        v8s bf[3];
        #pragma unroll
        for (int j=0;j<3;++j)
            bf[j] = ld8(BHI + ((nt0+j)*16 + l15)*384 + k0 + q8);
        #pragma unroll
        for (int i=0;i<6;++i)
            #pragma unroll
            for (int j=0;j<3;++j)
                acc[i][j] = MFMA(af[i], bf[j], acc[i][j]);
    }
    #pragma unroll
    for (int j=0;j<3;++j){
        int n = (nt0+j)*16 + l15;
        int s = n >= 192, h = n - s*192;
        if (h >= 180) continue;
        const int rb = (c*180 + h)*192 + s*96;
        #pragma unroll
        for (int i=0;i<6;++i)
            *(uint2*)(Sp + rb + i*16 + q4) = pk4(acc[i][j]);
    }
}

// ---------------------------------------------------------------------------
// gE v3: 2-D wave tile, role-swapped, residual in C-init.
//   block = 512 thr = 8 waves = 128 rows x 360 w.
//   wave  = (g = wid>>2) 64-row group x (qt = wid&3) 96-w quarter.
//   acc[r][j]: r = row subtile (16 rows), j = local w-tile; global tile
//   nt = qt*6+j (tile 23 multiplies BE's baked-zero rows; w>=360 lanes
//   guarded at x-init and store). Per ks: 6 BE + 4 Spec loads (L2-hot,
//   shared across waves/blocks) feed 24 MFMAs. x loads issue first and
//   overlap everything; epilogue is store-only float4.
__global__ __launch_bounds__(512, 2) void gE(const float* __restrict__ x,
                                             const short* __restrict__ Sp,
                                             const short* __restrict__ BE,
                                             float* __restrict__ out){
    const int b = blockIdx.x;
    const int tid = threadIdx.x, wid = tid >> 6, lane = tid & 63;
    const int l15 = lane & 15, q8 = (lane >> 4) << 3, q4 = q8 >> 1;
    const int R0 = b*128 + (wid >> 2)*64;           // wave's 64-row group
    const int qt = wid & 3;                         // w-quarter: tiles qt*6..qt*6+5
    v4f acc[4][6];
    #pragma unroll
    for (int r=0;r<4;++r){                          // C-init = x (overlaps GEMM)
        const int rbase = (R0 + r*16 + l15)*360;
        #pragma unroll
        for (int j=0;j<6;++j){
            const int w0 = (qt*6 + j)*16 + q4;
            if (w0 < 360){
                float4 xv = *(const float4*)(x + rbase + w0);
                acc[r][j][0]=xv.x; acc[r][j][1]=xv.y; acc[r][j][2]=xv.z; acc[r][j][3]=xv.w;
            } else {
                acc[r][j] = (v4f){0.f,0.f,0.f,0.f};
            }
        }
    }
    const short* Sr = Sp + (R0 + l15)*192;          // B-role: Spec row per lane
    const short* Bq = BE + (qt*96 + l15)*192;       // A-role: BE row (w) per lane
    #pragma unroll
    for (int ks=0; ks<6; ++ks){
        const int k0 = ks*32 + q8;
        v8s af[6];
        #pragma unroll
        for (int j=0;j<6;++j) af[j] = ld8(Bq + j*3072 + k0);
        v8s bf[4];
        #pragma unroll
        for (int r=0;r<4;++r) bf[r] = ld8(Sr + r*3072 + k0);
        #pragma unroll
        for (int r=0;r<4;++r)
            #pragma unroll
            for (int j=0;j<6;++j)
                acc[r][j] = MFMA(af[j], bf[r], acc[r][j]);
    }
    #pragma unroll
    for (int r=0;r<4;++r){                          // store-only epilogue
        const int rbase = (R0 + r*16 + l15)*360;
        #pragma unroll
        for (int j=0;j<6;++j){
            const int w0 = (qt*6 + j)*16 + q4;
            if (w0 < 360)
                *(float4*)(out + rbase + w0) =
                    make_float4(acc[r][j][0], acc[r][j][1], acc[r][j][2], acc[r][j][3]);
        }
    }
}

// ---------------------------------------------------------------------------
extern "C" void kernel_launch(void* const* d_in, const int* in_sizes, int n_in,
                              void* d_out, int out_size, void* d_ws, size_t ws_size,
                              hipStream_t stream){
    const float* x  = (const float*)d_in[0];
    const float* w1 = (const float*)d_in[1];
    const float* b1 = (const float*)d_in[2];
    const float* w2 = (const float*)d_in[3];
    const float* b2 = (const float*)d_in[4];
    float* out = (float*)d_out;
    short* ws = (short*)d_ws;
    short* B1 = ws;              // G1 then F3 (53.08 MB)
    short* B2 = ws + NBUF;       // F2 then Spec (53.08 MB)

    hipLaunchKernelGGL(bake, dim3((NBAKE+255)/256), dim3(256), 0, stream, w1, w2, ws);
    hipLaunchKernelGGL(gA,  dim3(1536),    dim3(256), 0, stream, x, B1, ws + OBA);
    hipLaunchKernelGGL(gHf, dim3(768),     dim3(512), 0, stream, B1, B2, ws + OBH);
    hipLaunchKernelGGL(gC,  dim3(270, 8),  dim3(256), 0, stream, B2, B1,
                       ws + OBW1, ws + OBW2, b1, b2);
    hipLaunchKernelGGL(gHi, dim3(768),     dim3(512), 0, stream, B1, B2, ws + OBHI);
    hipLaunchKernelGGL(gE,  dim3(1080),    dim3(512), 0, stream, x, B2, ws + OBE, out);
}

// Round 4
// 733.671 us; speedup vs baseline: 1.3435x; 1.1808x over previous
//
#include <hip/hip_runtime.h>
#include <math.h>

// ---------------------------------------------------------------------------
// AFNO2D as 5 bf16-MFMA GEMM stages + constant bake.
//   x:[1,768,180,360] f32. rfft2(ortho) -> per-mode blockdiag complex MLP
//   (8 blocks x 96ch, relu, softshrink, W-modes y<91 kept) -> irfft2 + x.
//
// GEMM forms (D = A*B, mfma_f32_16x16x32_bf16):
//  gA : per (c, h-half): D[m=h(96)][n=(s*96+y)(192)] = x-rows(K=384) * BA
//       store transposed -> G1[c][y][s*180+h]        (regs = 4 consecutive h)
//  gHf: per c: D[m=(s*192+h')(384)][n=y(96)] = BH(A) * G1-rows(B, K=384)
//       store -> F2[c2=2c+s][y*180+h']               (regs = 4 consecutive h')
//  gC : per (kb, 64-mode tile): Act(LDS-transposed from F2) * BW1 -> relu
//       -> *BW2 -> softshrink -> F3. WAVE = 64 modes x 48 outs (acc[4][3]):
//       per ks 4 Act LDS reads + 3 BW L2 loads feed 12 MFMAs, BW panels
//       read once per block (disjoint across waves, 4x less L2 traffic).
//  gHi: per c: D[m=y(96)][n=(s*192+h)(384)] = F3-rows(A) * BHI(B)
//       store -> Spec[(c*180+h)][s*96+y]             (regs = 4 consecutive y)
//  gE : ROLE-SWAPPED + 2-D wave tile: block = 8 waves = 128 rows x 360 w.
//       D[m=w][n=row] = BE-rows(A) * Spec-rows(B, K=192), C-init = x.
// Fragment layouts used (guide-verified): A[m=l&15][k=q*8+j],
// B[k=q*8+j][n=l&15], C/D[row=q*4+reg][col=l&15].
// ---------------------------------------------------------------------------

#define R360f 0.05270462766947299f   // 1/sqrt(360)
#define R180f 0.07453559924999299f   // 1/sqrt(180)
#define LAM   0.01f

typedef short v8s __attribute__((ext_vector_type(8)));
typedef float v4f __attribute__((ext_vector_type(4)));

#define MFMA(a,b,c) __builtin_amdgcn_mfma_f32_16x16x32_bf16(a,b,c,0,0,0)

// ws layout (shorts): BUF1 | BUF2 | BA | BH | BHI | BW1 | BW2 | BE
#define NBUF  26542080              // 53,084,160 B per ping-pong buffer
#define OBA   (2*NBUF)
#define OBH   (OBA + 73728)         // BA  [192][384]
#define OBHI  (OBH + 147456)        // BH  [384][384]
#define OBW1  (OBHI + 147456)       // BHI [384][384]
#define OBW2  (OBW1 + 294912)       // BW1 [8][192][192]
#define OBE   (OBW2 + 294912)       // BW2 [8][192][192]
#define NBAKE 1032192               // + BE [384][192]

static __device__ __forceinline__ short f2bs(float f){   // f32 -> bf16 (RNE)
    unsigned u = __builtin_bit_cast(unsigned, f);
    u = (u + 0x7fffu + ((u >> 16) & 1u)) >> 16;
    return (short)u;
}
static __device__ __forceinline__ v8s ld8(const short* p){
    return __builtin_bit_cast(v8s, *(const uint4*)p);
}
union PK { short s[4]; uint2 u; };
static __device__ __forceinline__ uint2 pk4(v4f a){
    PK t; t.s[0]=f2bs(a[0]); t.s[1]=f2bs(a[1]); t.s[2]=f2bs(a[2]); t.s[3]=f2bs(a[3]);
    return t.u;
}
union S8 { uint4 u; short s[8]; v8s v; };
static __device__ __forceinline__ float sshrink(float v){
    return (v > LAM) ? (v - LAM) : ((v < -LAM) ? (v + LAM) : 0.f);
}

// ---------------------------------------------------------------------------
__global__ __launch_bounds__(256) void bake(const float* __restrict__ w1,
                                            const float* __restrict__ w2,
                                            short* __restrict__ bt){
    int idx = blockIdx.x*256 + threadIdx.x;
    if (idx >= NBAKE) return;
    float v = 0.f;
    if (idx < 73728){                               // BA (B-role) [n=s*96+y][k=w]
        int n = idx/384, k = idx - n*384;
        int s = n >= 96, y = n - s*96;
        if (y < 91 && k < 360){
            float th = (float)((k*y) % 360) * 0.017453292519943295f;
            float sv, cv; sincosf(th, &sv, &cv);
            v = s ? -sv*R360f : cv*R360f;           // e^{-i th}
        }
        bt[OBA + idx] = f2bs(v); return;
    }
    idx -= 73728;
    if (idx < 147456){                              // BH (A-role) [m=s*192+h'][k=si*180+h]
        int m = idx/384, k = idx - m*384;
        int s = m >= 192, hp = m - s*192;
        if (hp < 180 && k < 360){
            int si = k >= 180; int h = k - si*180;
            float th = (float)((h*hp) % 180) * 0.03490658503988659f;
            float sv, cv; sincosf(th, &sv, &cv);
            v = R180f * (s == 0 ? (si == 0 ? cv : sv) : (si == 0 ? -sv : cv));
        }
        bt[OBH + idx] = f2bs(v); return;
    }
    idx -= 147456;
    if (idx < 147456){                              // BHI (B-role) [n=s*192+h][k=sp*180+h']
        int n = idx/384, k = idx - n*384;
        int s = n >= 192, h = n - s*192;
        if (h < 180 && k < 360){
            int sp = k >= 180; int hp = k - sp*180;
            float th = (float)((h*hp) % 180) * 0.03490658503988659f;
            float sv, cv; sincosf(th, &sv, &cv);
            v = R180f * (s == 0 ? (sp == 0 ? cv : -sv) : (sp == 0 ? sv : cv));
        }
        bt[OBHI + idx] = f2bs(v); return;
    }
    idx -= 147456;
    if (idx < 294912){                              // BW1 (B-role) [kb][n=2o+sp][k=2i+si]
        int kb = idx / 36864; int r = idx - kb*36864;
        int n = r / 192, k = r - n*192;
        int o = n >> 1, sp = n & 1, i = k >> 1, si = k & 1;
        const float* wp = w1 + ((((kb*96 + i)*96) + o) << 1);
        v = sp == 0 ? (si == 0 ? wp[0] : -wp[1]) : (si == 0 ? wp[1] : wp[0]);
        bt[OBW1 + idx] = f2bs(v); return;
    }
    idx -= 294912;
    if (idx < 294912){                              // BW2
        int kb = idx / 36864; int r = idx - kb*36864;
        int n = r / 192, k = r - n*192;
        int o = n >> 1, sp = n & 1, i = k >> 1, si = k & 1;
        const float* wp = w2 + ((((kb*96 + i)*96) + o) << 1);
        v = sp == 0 ? (si == 0 ? wp[0] : -wp[1]) : (si == 0 ? wp[1] : wp[0]);
        bt[OBW2 + idx] = f2bs(v); return;
    }
    idx -= 294912;
    {                                               // BE [w(384)][k=s*96+y]
        int w = idx / 192, k = idx - w*192;
        int s = k >= 96, y = k - s*96;
        if (w < 360 && y < 91){
            float th = (float)((y*w) % 360) * 0.017453292519943295f;
            float sv, cv; sincosf(th, &sv, &cv);
            v = (s == 0) ? (y == 0 ? 1.f : 2.f) * cv * R360f
                         : (y == 0 ? 0.f : -2.f*sv*R360f);
        }
        bt[OBE + idx] = f2bs(v);
    }
}

// ---------------------------------------------------------------------------
__global__ __launch_bounds__(256) void gA(const float* __restrict__ x,
                                          short* __restrict__ G1,
                                          const short* __restrict__ BA){
    const int b = blockIdx.x, c = b >> 1, hh = (b & 1)*96;
    const int tid = threadIdx.x, wid = tid >> 6, lane = tid & 63;
    const int l15 = lane & 15, q8 = (lane >> 4) << 3, q4 = q8 >> 1;
    const int nt0 = wid*3;
    const v4f vz = {0.f,0.f,0.f,0.f};
    v4f acc[6][3];
    #pragma unroll
    for (int i=0;i<6;++i){ acc[i][0]=vz; acc[i][1]=vz; acc[i][2]=vz; }
    for (int ks=0; ks<12; ++ks){
        const int k0 = ks*32;
        int kk = k0 + q8; if (kk >= 360) kk = 0;   // garbage * zero B-rows
        v8s af[6];
        #pragma unroll
        for (int mt=0; mt<6; ++mt){
            int h = hh + mt*16 + l15; if (h > 179) h = 179;  // rows>=180 dropped at store
            const float* xp = x + (c*180 + h)*360 + kk;
            float4 f0 = *(const float4*)xp;
            float4 f1 = *(const float4*)(xp + 4);
            S8 tt;
            tt.s[0]=f2bs(f0.x); tt.s[1]=f2bs(f0.y); tt.s[2]=f2bs(f0.z); tt.s[3]=f2bs(f0.w);
            tt.s[4]=f2bs(f1.x); tt.s[5]=f2bs(f1.y); tt.s[6]=f2bs(f1.z); tt.s[7]=f2bs(f1.w);
            af[mt] = tt.v;
        }
        v8s bf[3];
        #pragma unroll
        for (int j=0;j<3;++j)
            bf[j] = ld8(BA + ((nt0+j)*16 + l15)*384 + k0 + q8);
        #pragma unroll
        for (int mt=0; mt<6; ++mt)
            #pragma unroll
            for (int j=0;j<3;++j)
                acc[mt][j] = MFMA(af[mt], bf[j], acc[mt][j]);
    }
    #pragma unroll
    for (int mt=0; mt<6; ++mt){
        int hg = hh + mt*16 + q4;                   // 4-aligned, never straddles 180
        if (hg >= 180) continue;
        #pragma unroll
        for (int j=0;j<3;++j){
            int n = (nt0+j)*16 + l15;
            int s = n >= 96, y = n - s*96;
            *(uint2*)(G1 + (c*96 + y)*360 + s*180 + hg) = pk4(acc[mt][j]);
        }
    }
}

// ---------------------------------------------------------------------------
__global__ __launch_bounds__(512) void gHf(const short* __restrict__ G1,
                                           short* __restrict__ F2,
                                           const short* __restrict__ BH){
    const int c = blockIdx.x;
    const int tid = threadIdx.x, wid = tid >> 6, lane = tid & 63;
    const int l15 = lane & 15, q8 = (lane >> 4) << 3, q4 = q8 >> 1;
    const int mt0 = wid*3;
    const v4f vz = {0.f,0.f,0.f,0.f};
    v4f acc[3][6];
    #pragma unroll
    for (int i=0;i<3;++i)
        #pragma unroll
        for (int j=0;j<6;++j) acc[i][j]=vz;
    for (int ks=0; ks<12; ++ks){
        const int k0 = ks*32;
        int kk = k0 + q8; if (kk >= 360) kk = 0;
        v8s af[3];
        #pragma unroll
        for (int i=0;i<3;++i)
            af[i] = ld8(BH + ((mt0+i)*16 + l15)*384 + k0 + q8);
        v8s bf[6];
        #pragma unroll
        for (int j=0;j<6;++j)
            bf[j] = ld8(G1 + (c*96 + j*16 + l15)*360 + kk);
        #pragma unroll
        for (int i=0;i<3;++i)
            #pragma unroll
            for (int j=0;j<6;++j)
                acc[i][j] = MFMA(af[i], bf[j], acc[i][j]);
    }
    #pragma unroll
    for (int i=0;i<3;++i){
        int m = (mt0+i)*16 + q4;
        int s = m >= 192, hp = m - s*192;
        if (hp >= 180) continue;
        const int rb = (2*c + s)*17280 + hp;
        #pragma unroll
        for (int j=0;j<6;++j){
            int y = j*16 + l15;
            *(uint2*)(F2 + rb + y*180) = pk4(acc[i][j]);
        }
    }
}

// ---------------------------------------------------------------------------
// gC v2: wave = 64 modes x 48 outputs (acc[4][3]).
//   GEMM1: per ks, 4 Act LDS reads + 3 BW1 L2 loads -> 12 MFMAs; each BW
//   panel column-range is owned by exactly one wave (no redundant loads).
//   Barrier between O1 write and GEMM2 (waves read all O1 rows).
__global__ __launch_bounds__(256) void gC(const short* __restrict__ F2,
                                          short* __restrict__ F3,
                                          const short* __restrict__ BW1,
                                          const short* __restrict__ BW2,
                                          const float* __restrict__ b1,
                                          const float* __restrict__ b2){
    __shared__ short Act[64*200];    // [mode 64][ch2 192 + 8 pad]
    __shared__ short O1[64*200];
    const int mt = blockIdx.x, kb = blockIdx.y, m0 = mt*64;
    const int tid = threadIdx.x;
    #pragma unroll
    for (int i=0;i<6;++i){           // 1536 16B-chunks: transpose F2 -> Act
        int ch = tid + 256*i;
        int qq = ch / 192, rr = ch - qq*192;
        S8 tt; tt.u = *(const uint4*)(F2 + (kb*192 + rr)*17280 + m0 + qq*8);
        #pragma unroll
        for (int j=0;j<8;++j) Act[(qq*8+j)*200 + rr] = tt.s[j];  // consec lanes -> consec elems
    }
    __syncthreads();
    const int wid = tid >> 6, lane = tid & 63, l15 = lane & 15;
    const int q8 = (lane >> 4) << 3, q4 = q8 >> 1;
    const int nt0 = wid*3;                       // wave owns n = [wid*48, wid*48+48)
    const short* bw1 = BW1 + kb*36864;
    const short* bw2 = BW2 + kb*36864;
    const v4f vz = {0.f,0.f,0.f,0.f};
    v4f a1[4][3];
    #pragma unroll
    for (int mr=0;mr<4;++mr){ a1[mr][0]=vz; a1[mr][1]=vz; a1[mr][2]=vz; }
    for (int ks=0; ks<6; ++ks){
        const int k0 = ks*32 + q8;
        v8s af[4];
        #pragma unroll
        for (int mr=0;mr<4;++mr)
            af[mr] = __builtin_bit_cast(v8s, *(const uint4*)(Act + (mr*16 + l15)*200 + k0));
        v8s bf[3];
        #pragma unroll
        for (int j=0;j<3;++j)
            bf[j] = ld8(bw1 + ((nt0+j)*16 + l15)*192 + k0);
        #pragma unroll
        for (int mr=0;mr<4;++mr)
            #pragma unroll
            for (int j=0;j<3;++j)
                a1[mr][j] = MFMA(af[mr], bf[j], a1[mr][j]);
    }
    #pragma unroll
    for (int j=0;j<3;++j){
        int n = (nt0+j)*16 + l15;
        float bv = b1[(kb*96 + (n>>1))*2 + (n&1)];
        #pragma unroll
        for (int mr=0;mr<4;++mr)
            #pragma unroll
            for (int r=0;r<4;++r)
                O1[(mr*16 + q4 + r)*200 + n] = f2bs(fmaxf(a1[mr][j][r] + bv, 0.f));
    }
    __syncthreads();                 // waves read all O1 rows in GEMM2
    v4f a2[4][3];
    #pragma unroll
    for (int mr=0;mr<4;++mr){ a2[mr][0]=vz; a2[mr][1]=vz; a2[mr][2]=vz; }
    for (int ks=0; ks<6; ++ks){
        const int k0 = ks*32 + q8;
        v8s af[4];
        #pragma unroll
        for (int mr=0;mr<4;++mr)
            af[mr] = __builtin_bit_cast(v8s, *(const uint4*)(O1 + (mr*16 + l15)*200 + k0));
        v8s bf[3];
        #pragma unroll
        for (int j=0;j<3;++j)
            bf[j] = ld8(bw2 + ((nt0+j)*16 + l15)*192 + k0);
        #pragma unroll
        for (int mr=0;mr<4;++mr)
            #pragma unroll
            for (int j=0;j<3;++j)
                a2[mr][j] = MFMA(af[mr], bf[j], a2[mr][j]);
    }
    #pragma unroll
    for (int mr=0;mr<4;++mr){
        const int mb = m0 + mr*16 + q4;             // 4-aligned, never straddles 180
        const int y = mb / 180, hp = mb - y*180;
        #pragma unroll
        for (int j=0;j<3;++j){
            int n = (nt0+j)*16 + l15;
            int o = n >> 1, sp = n & 1;
            float bv = b2[(kb*96 + o)*2 + sp];
            v4f vv;
            #pragma unroll
            for (int r=0;r<4;++r) vv[r] = sshrink(a2[mr][j][r] + bv);
            *(uint2*)(F3 + ((kb*96 + o)*96 + y)*360 + sp*180 + hp) = pk4(vv);
        }
    }
}

// ---------------------------------------------------------------------------
__global__ __launch_bounds__(512) void gHi(const short* __restrict__ F3,
                                           short* __restrict__ Sp,
                                           const short* __restrict__ BHI){
    const int c = blockIdx.x;
    const int tid = threadIdx.x, wid = tid >> 6, lane = tid & 63;
    const int l15 = lane & 15, q8 = (lane >> 4) << 3, q4 = q8 >> 1;
    const int nt0 = wid*3;
    const v4f vz = {0.f,0.f,0.f,0.f};
    v4f acc[6][3];
    #pragma unroll
    for (int i=0;i<6;++i){ acc[i][0]=vz; acc[i][1]=vz; acc[i][2]=vz; }
    for (int ks=0; ks<12; ++ks){
        const int k0 = ks*32;
        int kk = k0 + q8; if (kk >= 360) kk = 0;
        v8s af[6];
        #pragma unroll
        for (int i=0;i<6;++i)
            af[i] = ld8(F3 + (c*96 + i*16 + l15)*360 + kk);
        v8s bf[3];
        #pragma unroll
        for (int j=0;j<3;++j)
            bf[j] = ld8(BHI + ((nt0+j)*16 + l15)*384 + k0 + q8);
        #pragma unroll
        for (int i=0;i<6;++i)
            #pragma unroll
            for (int j=0;j<3;++j)
                acc[i][j] = MFMA(af[i], bf[j], acc[i][j]);
    }
    #pragma unroll
    for (int j=0;j<3;++j){
        int n = (nt0+j)*16 + l15;
        int s = n >= 192, h = n - s*192;
        if (h >= 180) continue;
        const int rb = (c*180 + h)*192 + s*96;
        #pragma unroll
        for (int i=0;i<6;++i)
            *(uint2*)(Sp + rb + i*16 + q4) = pk4(acc[i][j]);
    }
}

// ---------------------------------------------------------------------------
// gE v3: 2-D wave tile, role-swapped, residual in C-init.
__global__ __launch_bounds__(512, 2) void gE(const float* __restrict__ x,
                                             const short* __restrict__ Sp,
                                             const short* __restrict__ BE,
                                             float* __restrict__ out){
    const int b = blockIdx.x;
    const int tid = threadIdx.x, wid = tid >> 6, lane = tid & 63;
    const int l15 = lane & 15, q8 = (lane >> 4) << 3, q4 = q8 >> 1;
    const int R0 = b*128 + (wid >> 2)*64;           // wave's 64-row group
    const int qt = wid & 3;                         // w-quarter: tiles qt*6..qt*6+5
    v4f acc[4][6];
    #pragma unroll
    for (int r=0;r<4;++r){                          // C-init = x (overlaps GEMM)
        const int rbase = (R0 + r*16 + l15)*360;
        #pragma unroll
        for (int j=0;j<6;++j){
            const int w0 = (qt*6 + j)*16 + q4;
            if (w0 < 360){
                float4 xv = *(const float4*)(x + rbase + w0);
                acc[r][j][0]=xv.x; acc[r][j][1]=xv.y; acc[r][j][2]=xv.z; acc[r][j][3]=xv.w;
            } else {
                acc[r][j] = (v4f){0.f,0.f,0.f,0.f};
            }
        }
    }
    const short* Sr = Sp + (R0 + l15)*192;          // B-role: Spec row per lane
    const short* Bq = BE + (qt*96 + l15)*192;       // A-role: BE row (w) per lane
    #pragma unroll
    for (int ks=0; ks<6; ++ks){
        const int k0 = ks*32 + q8;
        v8s af[6];
        #pragma unroll
        for (int j=0;j<6;++j) af[j] = ld8(Bq + j*3072 + k0);
        v8s bf[4];
        #pragma unroll
        for (int r=0;r<4;++r) bf[r] = ld8(Sr + r*3072 + k0);
        #pragma unroll
        for (int r=0;r<4;++r)
            #pragma unroll
            for (int j=0;j<6;++j)
                acc[r][j] = MFMA(af[j], bf[r], acc[r][j]);
    }
    #pragma unroll
    for (int r=0;r<4;++r){                          // store-only epilogue
        const int rbase = (R0 + r*16 + l15)*360;
        #pragma unroll
        for (int j=0;j<6;++j){
            const int w0 = (qt*6 + j)*16 + q4;
            if (w0 < 360)
                *(float4*)(out + rbase + w0) =
                    make_float4(acc[r][j][0], acc[r][j][1], acc[r][j][2], acc[r][j][3]);
        }
    }
}

// ---------------------------------------------------------------------------
extern "C" void kernel_launch(void* const* d_in, const int* in_sizes, int n_in,
                              void* d_out, int out_size, void* d_ws, size_t ws_size,
                              hipStream_t stream){
    const float* x  = (const float*)d_in[0];
    const float* w1 = (const float*)d_in[1];
    const float* b1 = (const float*)d_in[2];
    const float* w2 = (const float*)d_in[3];
    const float* b2 = (const float*)d_in[4];
    float* out = (float*)d_out;
    short* ws = (short*)d_ws;
    short* B1 = ws;              // G1 then F3 (53.08 MB)
    short* B2 = ws + NBUF;       // F2 then Spec (53.08 MB)

    hipLaunchKernelGGL(bake, dim3((NBAKE+255)/256), dim3(256), 0, stream, w1, w2, ws);
    hipLaunchKernelGGL(gA,  dim3(1536),    dim3(256), 0, stream, x, B1, ws + OBA);
    hipLaunchKernelGGL(gHf, dim3(768),     dim3(512), 0, stream, B1, B2, ws + OBH);
    hipLaunchKernelGGL(gC,  dim3(270, 8),  dim3(256), 0, stream, B2, B1,
                       ws + OBW1, ws + OBW2, b1, b2);
    hipLaunchKernelGGL(gHi, dim3(768),     dim3(512), 0, stream, B1, B2, ws + OBHI);
    hipLaunchKernelGGL(gE,  dim3(1080),    dim3(512), 0, stream, x, B2, ws + OBE, out);
}

// Round 5
// 662.594 us; speedup vs baseline: 1.4876x; 1.1073x over previous
//
#include <hip/hip_runtime.h>
#include <math.h>

// ---------------------------------------------------------------------------
// AFNO2D as 5 bf16-MFMA GEMM stages + constant bake.
//   x:[1,768,180,360] f32. rfft2(ortho) -> per-mode blockdiag complex MLP
//   (8 blocks x 96ch, relu, softshrink, W-modes y<91 kept) -> irfft2 + x.
//
// GEMM forms (D = A*B, mfma_f32_16x16x32_bf16):
//  gA : per (c, h-half): D[m=h(96)][n=(s*96+y)(192)] = x-rows(K=384) * BA.
//       x panel LDS-staged once/block (bf16, converted once, coalesced);
//       A-frags from LDS, store transposed -> G1[c][y][s*180+h].
//  gHf: per c: D[m=(s*192+h')(384)][n=y(96)] = BH(A) * G1-rows(B, K=384).
//       G1 panel LDS-staged once/block; B-frags from LDS -> F2[2c+s][y*180+h'].
//  gC : per (kb, 64-mode tile): Act(LDS-transposed from F2) * BW1 -> relu
//       -> *BW2 -> softshrink -> F3. Wave = 64 modes x 48 outs (acc[4][3]).
//  gHi: per c: D[m=y(96)][n=(s*192+h)(384)] = F3-rows(A) * BHI(B).
//       F3 panel LDS-staged once/block; A-frags from LDS -> Spec.
//  gE : ROLE-SWAPPED + 2-D wave tile: block = 8 waves = 128 rows x 360 w.
//       D[m=w][n=row] = BE-rows(A) * Spec-rows(B, K=192), C-init = x.
// LDS panels are [96][392] (row stride 784 B = 4-bank shift/row -> free
// 2-way conflict on ds_read_b128); cols 360..383 hold wrapped garbage
// that baked zero rows/cols of BA/BH/BHI annihilate.
// Fragment layouts used (guide-verified): A[m=l&15][k=q*8+j],
// B[k=q*8+j][n=l&15], C/D[row=q*4+reg][col=l&15].
// ---------------------------------------------------------------------------

#define R360f 0.05270462766947299f   // 1/sqrt(360)
#define R180f 0.07453559924999299f   // 1/sqrt(180)
#define LAM   0.01f

typedef short v8s __attribute__((ext_vector_type(8)));
typedef float v4f __attribute__((ext_vector_type(4)));

#define MFMA(a,b,c) __builtin_amdgcn_mfma_f32_16x16x32_bf16(a,b,c,0,0,0)

// ws layout (shorts): BUF1 | BUF2 | BA | BH | BHI | BW1 | BW2 | BE
#define NBUF  26542080              // 53,084,160 B per ping-pong buffer
#define OBA   (2*NBUF)
#define OBH   (OBA + 73728)         // BA  [192][384]
#define OBHI  (OBH + 147456)        // BH  [384][384]
#define OBW1  (OBHI + 147456)       // BHI [384][384]
#define OBW2  (OBW1 + 294912)       // BW1 [8][192][192]
#define OBE   (OBW2 + 294912)       // BW2 [8][192][192]
#define NBAKE 1032192               // + BE [384][192]

static __device__ __forceinline__ short f2bs(float f){   // f32 -> bf16 (RNE)
    unsigned u = __builtin_bit_cast(unsigned, f);
    u = (u + 0x7fffu + ((u >> 16) & 1u)) >> 16;
    return (short)u;
}
static __device__ __forceinline__ v8s ld8(const short* p){
    return __builtin_bit_cast(v8s, *(const uint4*)p);
}
static __device__ __forceinline__ v8s ld8s(const short* p){  // LDS 16B read
    return __builtin_bit_cast(v8s, *(const uint4*)p);
}
union PK { short s[4]; uint2 u; };
static __device__ __forceinline__ uint2 pk4(v4f a){
    PK t; t.s[0]=f2bs(a[0]); t.s[1]=f2bs(a[1]); t.s[2]=f2bs(a[2]); t.s[3]=f2bs(a[3]);
    return t.u;
}
union S8 { uint4 u; short s[8]; v8s v; };
static __device__ __forceinline__ float sshrink(float v){
    return (v > LAM) ? (v - LAM) : ((v < -LAM) ? (v + LAM) : 0.f);
}

// ---------------------------------------------------------------------------
__global__ __launch_bounds__(256) void bake(const float* __restrict__ w1,
                                            const float* __restrict__ w2,
                                            short* __restrict__ bt){
    int idx = blockIdx.x*256 + threadIdx.x;
    if (idx >= NBAKE) return;
    float v = 0.f;
    if (idx < 73728){                               // BA (B-role) [n=s*96+y][k=w]
        int n = idx/384, k = idx - n*384;
        int s = n >= 96, y = n - s*96;
        if (y < 91 && k < 360){
            float th = (float)((k*y) % 360) * 0.017453292519943295f;
            float sv, cv; sincosf(th, &sv, &cv);
            v = s ? -sv*R360f : cv*R360f;           // e^{-i th}
        }
        bt[OBA + idx] = f2bs(v); return;
    }
    idx -= 73728;
    if (idx < 147456){                              // BH (A-role) [m=s*192+h'][k=si*180+h]
        int m = idx/384, k = idx - m*384;
        int s = m >= 192, hp = m - s*192;
        if (hp < 180 && k < 360){
            int si = k >= 180; int h = k - si*180;
            float th = (float)((h*hp) % 180) * 0.03490658503988659f;
            float sv, cv; sincosf(th, &sv, &cv);
            v = R180f * (s == 0 ? (si == 0 ? cv : sv) : (si == 0 ? -sv : cv));
        }
        bt[OBH + idx] = f2bs(v); return;
    }
    idx -= 147456;
    if (idx < 147456){                              // BHI (B-role) [n=s*192+h][k=sp*180+h']
        int n = idx/384, k = idx - n*384;
        int s = n >= 192, h = n - s*192;
        if (h < 180 && k < 360){
            int sp = k >= 180; int hp = k - sp*180;
            float th = (float)((h*hp) % 180) * 0.03490658503988659f;
            float sv, cv; sincosf(th, &sv, &cv);
            v = R180f * (s == 0 ? (sp == 0 ? cv : -sv) : (sp == 0 ? sv : cv));
        }
        bt[OBHI + idx] = f2bs(v); return;
    }
    idx -= 147456;
    if (idx < 294912){                              // BW1 (B-role) [kb][n=2o+sp][k=2i+si]
        int kb = idx / 36864; int r = idx - kb*36864;
        int n = r / 192, k = r - n*192;
        int o = n >> 1, sp = n & 1, i = k >> 1, si = k & 1;
        const float* wp = w1 + ((((kb*96 + i)*96) + o) << 1);
        v = sp == 0 ? (si == 0 ? wp[0] : -wp[1]) : (si == 0 ? wp[1] : wp[0]);
        bt[OBW1 + idx] = f2bs(v); return;
    }
    idx -= 294912;
    if (idx < 294912){                              // BW2
        int kb = idx / 36864; int r = idx - kb*36864;
        int n = r / 192, k = r - n*192;
        int o = n >> 1, sp = n & 1, i = k >> 1, si = k & 1;
        const float* wp = w2 + ((((kb*96 + i)*96) + o) << 1);
        v = sp == 0 ? (si == 0 ? wp[0] : -wp[1]) : (si == 0 ? wp[1] : wp[0]);
        bt[OBW2 + idx] = f2bs(v); return;
    }
    idx -= 294912;
    {                                               // BE [w(384)][k=s*96+y]
        int w = idx / 192, k = idx - w*192;
        int s = k >= 96, y = k - s*96;
        if (w < 360 && y < 91){
            float th = (float)((y*w) % 360) * 0.017453292519943295f;
            float sv, cv; sincosf(th, &sv, &cv);
            v = (s == 0) ? (y == 0 ? 1.f : 2.f) * cv * R360f
                         : (y == 0 ? 0.f : -2.f*sv*R360f);
        }
        bt[OBE + idx] = f2bs(v);
    }
}

// ---------------------------------------------------------------------------
// gA v2: x panel staged to LDS (bf16) once per block, coalesced, converted
// once. K-loop A-frags are LDS reads; only BA (L2-hot) comes from global.
__global__ __launch_bounds__(256) void gA(const float* __restrict__ x,
                                          short* __restrict__ G1,
                                          const short* __restrict__ BA){
    __shared__ short X[96*392];
    const int b = blockIdx.x, c = b >> 1, hh = (b & 1)*96;
    const int tid = threadIdx.x, wid = tid >> 6, lane = tid & 63;
    const int l15 = lane & 15, q8 = (lane >> 4) << 3, q4 = q8 >> 1;
    const int nt0 = wid*3;
    // stage: 96 rows x 384 cols in float4 chunks (9216), coalesced in col
    #pragma unroll
    for (int i=0;i<36;++i){
        int idx = tid + 256*i;
        int row = idx / 96, ch = idx - row*96;
        int col = ch*4;
        int cc = col < 360 ? col : col - 360;       // wrapped garbage * zero BA
        int h = hh + row; if (h > 179) h = 179;     // rows>=180 dropped at store
        float4 f = *(const float4*)(x + (c*180 + h)*360 + cc);
        PK t; t.s[0]=f2bs(f.x); t.s[1]=f2bs(f.y); t.s[2]=f2bs(f.z); t.s[3]=f2bs(f.w);
        *(uint2*)(X + row*392 + col) = t.u;
    }
    __syncthreads();
    const v4f vz = {0.f,0.f,0.f,0.f};
    v4f acc[6][3];
    #pragma unroll
    for (int i=0;i<6;++i){ acc[i][0]=vz; acc[i][1]=vz; acc[i][2]=vz; }
    for (int ks=0; ks<12; ++ks){
        const int k0 = ks*32 + q8;
        v8s af[6];
        #pragma unroll
        for (int mt=0; mt<6; ++mt)
            af[mt] = ld8s(X + (mt*16 + l15)*392 + k0);
        v8s bf[3];
        #pragma unroll
        for (int j=0;j<3;++j)
            bf[j] = ld8(BA + ((nt0+j)*16 + l15)*384 + k0);
        #pragma unroll
        for (int mt=0; mt<6; ++mt)
            #pragma unroll
            for (int j=0;j<3;++j)
                acc[mt][j] = MFMA(af[mt], bf[j], acc[mt][j]);
    }
    #pragma unroll
    for (int mt=0; mt<6; ++mt){
        int hg = hh + mt*16 + q4;                   // 4-aligned, never straddles 180
        if (hg >= 180) continue;
        #pragma unroll
        for (int j=0;j<3;++j){
            int n = (nt0+j)*16 + l15;
            int s = n >= 96, y = n - s*96;
            *(uint2*)(G1 + (c*96 + y)*360 + s*180 + hg) = pk4(acc[mt][j]);
        }
    }
}

// ---------------------------------------------------------------------------
// gHf v2: G1 panel (shared by all 8 waves as B-operand) staged to LDS once.
__global__ __launch_bounds__(512) void gHf(const short* __restrict__ G1,
                                           short* __restrict__ F2,
                                           const short* __restrict__ BH){
    __shared__ short G[96*392];
    const int c = blockIdx.x;
    const int tid = threadIdx.x, wid = tid >> 6, lane = tid & 63;
    const int l15 = lane & 15, q8 = (lane >> 4) << 3, q4 = q8 >> 1;
    const int mt0 = wid*3;
    // stage: 96 rows x 384 cols bf16 in uint4 chunks (4608), coalesced
    #pragma unroll
    for (int i=0;i<9;++i){
        int idx = tid + 512*i;
        int row = idx / 48, ch = idx - row*48;
        int col = ch*8;
        int cc = col < 360 ? col : col - 360;       // wrapped garbage * zero BH
        *(uint4*)(G + row*392 + col) = *(const uint4*)(G1 + (c*96 + row)*360 + cc);
    }
    __syncthreads();
    const v4f vz = {0.f,0.f,0.f,0.f};
    v4f acc[3][6];
    #pragma unroll
    for (int i=0;i<3;++i)
        #pragma unroll
        for (int j=0;j<6;++j) acc[i][j]=vz;
    for (int ks=0; ks<12; ++ks){
        const int k0 = ks*32 + q8;
        v8s af[3];
        #pragma unroll
        for (int i=0;i<3;++i)
            af[i] = ld8(BH + ((mt0+i)*16 + l15)*384 + k0);
        v8s bf[6];
        #pragma unroll
        for (int j=0;j<6;++j)
            bf[j] = ld8s(G + (j*16 + l15)*392 + k0);
        #pragma unroll
        for (int i=0;i<3;++i)
            #pragma unroll
            for (int j=0;j<6;++j)
                acc[i][j] = MFMA(af[i], bf[j], acc[i][j]);
    }
    #pragma unroll
    for (int i=0;i<3;++i){
        int m = (mt0+i)*16 + q4;
        int s = m >= 192, hp = m - s*192;
        if (hp >= 180) continue;
        const int rb = (2*c + s)*17280 + hp;
        #pragma unroll
        for (int j=0;j<6;++j){
            int y = j*16 + l15;
            *(uint2*)(F2 + rb + y*180) = pk4(acc[i][j]);
        }
    }
}

// ---------------------------------------------------------------------------
// gC v2: wave = 64 modes x 48 outputs (acc[4][3]).
__global__ __launch_bounds__(256) void gC(const short* __restrict__ F2,
                                          short* __restrict__ F3,
                                          const short* __restrict__ BW1,
                                          const short* __restrict__ BW2,
                                          const float* __restrict__ b1,
                                          const float* __restrict__ b2){
    __shared__ short Act[64*200];    // [mode 64][ch2 192 + 8 pad]
    __shared__ short O1[64*200];
    const int mt = blockIdx.x, kb = blockIdx.y, m0 = mt*64;
    const int tid = threadIdx.x;
    #pragma unroll
    for (int i=0;i<6;++i){           // 1536 16B-chunks: transpose F2 -> Act
        int ch = tid + 256*i;
        int qq = ch / 192, rr = ch - qq*192;
        S8 tt; tt.u = *(const uint4*)(F2 + (kb*192 + rr)*17280 + m0 + qq*8);
        #pragma unroll
        for (int j=0;j<8;++j) Act[(qq*8+j)*200 + rr] = tt.s[j];  // consec lanes -> consec elems
    }
    __syncthreads();
    const int wid = tid >> 6, lane = tid & 63, l15 = lane & 15;
    const int q8 = (lane >> 4) << 3, q4 = q8 >> 1;
    const int nt0 = wid*3;                       // wave owns n = [wid*48, wid*48+48)
    const short* bw1 = BW1 + kb*36864;
    const short* bw2 = BW2 + kb*36864;
    const v4f vz = {0.f,0.f,0.f,0.f};
    v4f a1[4][3];
    #pragma unroll
    for (int mr=0;mr<4;++mr){ a1[mr][0]=vz; a1[mr][1]=vz; a1[mr][2]=vz; }
    for (int ks=0; ks<6; ++ks){
        const int k0 = ks*32 + q8;
        v8s af[4];
        #pragma unroll
        for (int mr=0;mr<4;++mr)
            af[mr] = __builtin_bit_cast(v8s, *(const uint4*)(Act + (mr*16 + l15)*200 + k0));
        v8s bf[3];
        #pragma unroll
        for (int j=0;j<3;++j)
            bf[j] = ld8(bw1 + ((nt0+j)*16 + l15)*192 + k0);
        #pragma unroll
        for (int mr=0;mr<4;++mr)
            #pragma unroll
            for (int j=0;j<3;++j)
                a1[mr][j] = MFMA(af[mr], bf[j], a1[mr][j]);
    }
    #pragma unroll
    for (int j=0;j<3;++j){
        int n = (nt0+j)*16 + l15;
        float bv = b1[(kb*96 + (n>>1))*2 + (n&1)];
        #pragma unroll
        for (int mr=0;mr<4;++mr)
            #pragma unroll
            for (int r=0;r<4;++r)
                O1[(mr*16 + q4 + r)*200 + n] = f2bs(fmaxf(a1[mr][j][r] + bv, 0.f));
    }
    __syncthreads();                 // waves read all O1 rows in GEMM2
    v4f a2[4][3];
    #pragma unroll
    for (int mr=0;mr<4;++mr){ a2[mr][0]=vz; a2[mr][1]=vz; a2[mr][2]=vz; }
    for (int ks=0; ks<6; ++ks){
        const int k0 = ks*32 + q8;
        v8s af[4];
        #pragma unroll
        for (int mr=0;mr<4;++mr)
            af[mr] = __builtin_bit_cast(v8s, *(const uint4*)(O1 + (mr*16 + l15)*200 + k0));
        v8s bf[3];
        #pragma unroll
        for (int j=0;j<3;++j)
            bf[j] = ld8(bw2 + ((nt0+j)*16 + l15)*192 + k0);
        #pragma unroll
        for (int mr=0;mr<4;++mr)
            #pragma unroll
            for (int j=0;j<3;++j)
                a2[mr][j] = MFMA(af[mr], bf[j], a2[mr][j]);
    }
    #pragma unroll
    for (int mr=0;mr<4;++mr){
        const int mb = m0 + mr*16 + q4;             // 4-aligned, never straddles 180
        const int y = mb / 180, hp = mb - y*180;
        #pragma unroll
        for (int j=0;j<3;++j){
            int n = (nt0+j)*16 + l15;
            int o = n >> 1, sp = n & 1;
            float bv = b2[(kb*96 + o)*2 + sp];
            v4f vv;
            #pragma unroll
            for (int r=0;r<4;++r) vv[r] = sshrink(a2[mr][j][r] + bv);
            *(uint2*)(F3 + ((kb*96 + o)*96 + y)*360 + sp*180 + hp) = pk4(vv);
        }
    }
}

// ---------------------------------------------------------------------------
// gHi v2: F3 panel (shared by all 8 waves as A-operand) staged to LDS once.
__global__ __launch_bounds__(512) void gHi(const short* __restrict__ F3,
                                           short* __restrict__ Sp,
                                           const short* __restrict__ BHI){
    __shared__ short F[96*392];
    const int c = blockIdx.x;
    const int tid = threadIdx.x, wid = tid >> 6, lane = tid & 63;
    const int l15 = lane & 15, q8 = (lane >> 4) << 3, q4 = q8 >> 1;
    const int nt0 = wid*3;
    #pragma unroll
    for (int i=0;i<9;++i){
        int idx = tid + 512*i;
        int row = idx / 48, ch = idx - row*48;
        int col = ch*8;
        int cc = col < 360 ? col : col - 360;       // wrapped garbage * zero BHI
        *(uint4*)(F + row*392 + col) = *(const uint4*)(F3 + (c*96 + row)*360 + cc);
    }
    __syncthreads();
    const v4f vz = {0.f,0.f,0.f,0.f};
    v4f acc[6][3];
    #pragma unroll
    for (int i=0;i<6;++i){ acc[i][0]=vz; acc[i][1]=vz; acc[i][2]=vz; }
    for (int ks=0; ks<12; ++ks){
        const int k0 = ks*32 + q8;
        v8s af[6];
        #pragma unroll
        for (int i=0;i<6;++i)
            af[i] = ld8s(F + (i*16 + l15)*392 + k0);
        v8s bf[3];
        #pragma unroll
        for (int j=0;j<3;++j)
            bf[j] = ld8(BHI + ((nt0+j)*16 + l15)*384 + k0);
        #pragma unroll
        for (int i=0;i<6;++i)
            #pragma unroll
            for (int j=0;j<3;++j)
                acc[i][j] = MFMA(af[i], bf[j], acc[i][j]);
    }
    #pragma unroll
    for (int j=0;j<3;++j){
        int n = (nt0+j)*16 + l15;
        int s = n >= 192, h = n - s*192;
        if (h >= 180) continue;
        const int rb = (c*180 + h)*192 + s*96;
        #pragma unroll
        for (int i=0;i<6;++i)
            *(uint2*)(Sp + rb + i*16 + q4) = pk4(acc[i][j]);
    }
}

// ---------------------------------------------------------------------------
// gE v3: 2-D wave tile, role-swapped, residual in C-init.
__global__ __launch_bounds__(512, 2) void gE(const float* __restrict__ x,
                                             const short* __restrict__ Sp,
                                             const short* __restrict__ BE,
                                             float* __restrict__ out){
    const int b = blockIdx.x;
    const int tid = threadIdx.x, wid = tid >> 6, lane = tid & 63;
    const int l15 = lane & 15, q8 = (lane >> 4) << 3, q4 = q8 >> 1;
    const int R0 = b*128 + (wid >> 2)*64;           // wave's 64-row group
    const int qt = wid & 3;                         // w-quarter: tiles qt*6..qt*6+5
    v4f acc[4][6];
    #pragma unroll
    for (int r=0;r<4;++r){                          // C-init = x (overlaps GEMM)
        const int rbase = (R0 + r*16 + l15)*360;
        #pragma unroll
        for (int j=0;j<6;++j){
            const int w0 = (qt*6 + j)*16 + q4;
            if (w0 < 360){
                float4 xv = *(const float4*)(x + rbase + w0);
                acc[r][j][0]=xv.x; acc[r][j][1]=xv.y; acc[r][j][2]=xv.z; acc[r][j][3]=xv.w;
            } else {
                acc[r][j] = (v4f){0.f,0.f,0.f,0.f};
            }
        }
    }
    const short* Sr = Sp + (R0 + l15)*192;          // B-role: Spec row per lane
    const short* Bq = BE + (qt*96 + l15)*192;       // A-role: BE row (w) per lane
    #pragma unroll
    for (int ks=0; ks<6; ++ks){
        const int k0 = ks*32 + q8;
        v8s af[6];
        #pragma unroll
        for (int j=0;j<6;++j) af[j] = ld8(Bq + j*3072 + k0);
        v8s bf[4];
        #pragma unroll
        for (int r=0;r<4;++r) bf[r] = ld8(Sr + r*3072 + k0);
        #pragma unroll
        for (int r=0;r<4;++r)
            #pragma unroll
            for (int j=0;j<6;++j)
                acc[r][j] = MFMA(af[j], bf[r], acc[r][j]);
    }
    #pragma unroll
    for (int r=0;r<4;++r){                          // store-only epilogue
        const int rbase = (R0 + r*16 + l15)*360;
        #pragma unroll
        for (int j=0;j<6;++j){
            const int w0 = (qt*6 + j)*16 + q4;
            if (w0 < 360)
                *(float4*)(out + rbase + w0) =
                    make_float4(acc[r][j][0], acc[r][j][1], acc[r][j][2], acc[r][j][3]);
        }
    }
}

// ---------------------------------------------------------------------------
extern "C" void kernel_launch(void* const* d_in, const int* in_sizes, int n_in,
                              void* d_out, int out_size, void* d_ws, size_t ws_size,
                              hipStream_t stream){
    const float* x  = (const float*)d_in[0];
    const float* w1 = (const float*)d_in[1];
    const float* b1 = (const float*)d_in[2];
    const float* w2 = (const float*)d_in[3];
    const float* b2 = (const float*)d_in[4];
    float* out = (float*)d_out;
    short* ws = (short*)d_ws;
    short* B1 = ws;              // G1 then F3 (53.08 MB)
    short* B2 = ws + NBUF;       // F2 then Spec (53.08 MB)

    hipLaunchKernelGGL(bake, dim3((NBAKE+255)/256), dim3(256), 0, stream, w1, w2, ws);
    hipLaunchKernelGGL(gA,  dim3(1536),    dim3(256), 0, stream, x, B1, ws + OBA);
    hipLaunchKernelGGL(gHf, dim3(768),     dim3(512), 0, stream, B1, B2, ws + OBH);
    hipLaunchKernelGGL(gC,  dim3(270, 8),  dim3(256), 0, stream, B2, B1,
                       ws + OBW1, ws + OBW2, b1, b2);
    hipLaunchKernelGGL(gHi, dim3(768),     dim3(512), 0, stream, B1, B2, ws + OBHI);
    hipLaunchKernelGGL(gE,  dim3(1080),    dim3(512), 0, stream, x, B2, ws + OBE, out);
}

// Round 6
// 654.100 us; speedup vs baseline: 1.5069x; 1.0130x over previous
//
#include <hip/hip_runtime.h>
#include <math.h>

// ---------------------------------------------------------------------------
// AFNO2D as 5 bf16-MFMA GEMM stages + constant bake.
//   x:[1,768,180,360] f32. rfft2(ortho) -> per-mode blockdiag complex MLP
//   (8 blocks x 96ch, relu, softshrink, W-modes y<91 kept) -> irfft2 + x.
//
// GEMM forms (D = A*B, mfma_f32_16x16x32_bf16):
//  gA : per (c, h-half): D[m=h(96)][n=(s*96+y)(192)] = x-rows(K=384) * BA.
//       x panel LDS-staged once/block (bf16, converted once, coalesced);
//       A-frags from LDS, store transposed -> G1[c][y][s*180+h].
//  gHf: per c: D[m=(s*192+h')(384)][n=y(96)] = BH(A) * G1-rows(B, K=384).
//       G1 panel LDS-staged once/block; B-frags from LDS -> F2[2c+s][y*180+h'].
//  gC : per (kb, 64-mode tile): Act(LDS-transposed from F2) * BW1 -> relu
//       -> *BW2 -> softshrink -> F3. Wave = 64 modes x 48 outs (acc[4][3]).
//  gHi: per c: D[m=y(96)][n=(s*192+h)(384)] = F3-rows(A) * BHI(B).
//       F3 panel LDS-staged once/block; A-frags from LDS -> Spec.
//  gE : ROLE-SWAPPED 2-D wave tile, 4-wave blocks for phase stagger:
//       block = 64 rows x 360 w; wave = 64 rows x 96 w (acc[4][6]).
//       D[m=w][n=row] = BE-rows(A) * Spec-rows(B, K=192), C-init = x.
//       Small blocks -> 4-5 blocks/CU resident in different phases, so
//       loads/stores of one block overlap MFMA of another (HBM duty up).
// LDS panels are [96][392] (row stride 784 B = 4-bank shift/row -> free
// 2-way conflict on ds_read_b128); cols 360..383 hold wrapped garbage
// that baked zero rows/cols of BA/BH/BHI annihilate.
// Fragment layouts used (guide-verified): A[m=l&15][k=q*8+j],
// B[k=q*8+j][n=l&15], C/D[row=q*4+reg][col=l&15].
// ---------------------------------------------------------------------------

#define R360f 0.05270462766947299f   // 1/sqrt(360)
#define R180f 0.07453559924999299f   // 1/sqrt(180)
#define LAM   0.01f

typedef short v8s __attribute__((ext_vector_type(8)));
typedef float v4f __attribute__((ext_vector_type(4)));

#define MFMA(a,b,c) __builtin_amdgcn_mfma_f32_16x16x32_bf16(a,b,c,0,0,0)

// ws layout (shorts): BUF1 | BUF2 | BA | BH | BHI | BW1 | BW2 | BE
#define NBUF  26542080              // 53,084,160 B per ping-pong buffer
#define OBA   (2*NBUF)
#define OBH   (OBA + 73728)         // BA  [192][384]
#define OBHI  (OBH + 147456)        // BH  [384][384]
#define OBW1  (OBHI + 147456)       // BHI [384][384]
#define OBW2  (OBW1 + 294912)       // BW1 [8][192][192]
#define OBE   (OBW2 + 294912)       // BW2 [8][192][192]
#define NBAKE 1032192               // + BE [384][192]

static __device__ __forceinline__ short f2bs(float f){   // f32 -> bf16 (RNE)
    unsigned u = __builtin_bit_cast(unsigned, f);
    u = (u + 0x7fffu + ((u >> 16) & 1u)) >> 16;
    return (short)u;
}
static __device__ __forceinline__ v8s ld8(const short* p){
    return __builtin_bit_cast(v8s, *(const uint4*)p);
}
static __device__ __forceinline__ v8s ld8s(const short* p){  // LDS 16B read
    return __builtin_bit_cast(v8s, *(const uint4*)p);
}
union PK { short s[4]; uint2 u; };
static __device__ __forceinline__ uint2 pk4(v4f a){
    PK t; t.s[0]=f2bs(a[0]); t.s[1]=f2bs(a[1]); t.s[2]=f2bs(a[2]); t.s[3]=f2bs(a[3]);
    return t.u;
}
union S8 { uint4 u; short s[8]; v8s v; };
static __device__ __forceinline__ float sshrink(float v){
    return (v > LAM) ? (v - LAM) : ((v < -LAM) ? (v + LAM) : 0.f);
}

// ---------------------------------------------------------------------------
__global__ __launch_bounds__(256) void bake(const float* __restrict__ w1,
                                            const float* __restrict__ w2,
                                            short* __restrict__ bt){
    int idx = blockIdx.x*256 + threadIdx.x;
    if (idx >= NBAKE) return;
    float v = 0.f;
    if (idx < 73728){                               // BA (B-role) [n=s*96+y][k=w]
        int n = idx/384, k = idx - n*384;
        int s = n >= 96, y = n - s*96;
        if (y < 91 && k < 360){
            float th = (float)((k*y) % 360) * 0.017453292519943295f;
            float sv, cv; sincosf(th, &sv, &cv);
            v = s ? -sv*R360f : cv*R360f;           // e^{-i th}
        }
        bt[OBA + idx] = f2bs(v); return;
    }
    idx -= 73728;
    if (idx < 147456){                              // BH (A-role) [m=s*192+h'][k=si*180+h]
        int m = idx/384, k = idx - m*384;
        int s = m >= 192, hp = m - s*192;
        if (hp < 180 && k < 360){
            int si = k >= 180; int h = k - si*180;
            float th = (float)((h*hp) % 180) * 0.03490658503988659f;
            float sv, cv; sincosf(th, &sv, &cv);
            v = R180f * (s == 0 ? (si == 0 ? cv : sv) : (si == 0 ? -sv : cv));
        }
        bt[OBH + idx] = f2bs(v); return;
    }
    idx -= 147456;
    if (idx < 147456){                              // BHI (B-role) [n=s*192+h][k=sp*180+h']
        int n = idx/384, k = idx - n*384;
        int s = n >= 192, h = n - s*192;
        if (h < 180 && k < 360){
            int sp = k >= 180; int hp = k - sp*180;
            float th = (float)((h*hp) % 180) * 0.03490658503988659f;
            float sv, cv; sincosf(th, &sv, &cv);
            v = R180f * (s == 0 ? (sp == 0 ? cv : -sv) : (sp == 0 ? sv : cv));
        }
        bt[OBHI + idx] = f2bs(v); return;
    }
    idx -= 147456;
    if (idx < 294912){                              // BW1 (B-role) [kb][n=2o+sp][k=2i+si]
        int kb = idx / 36864; int r = idx - kb*36864;
        int n = r / 192, k = r - n*192;
        int o = n >> 1, sp = n & 1, i = k >> 1, si = k & 1;
        const float* wp = w1 + ((((kb*96 + i)*96) + o) << 1);
        v = sp == 0 ? (si == 0 ? wp[0] : -wp[1]) : (si == 0 ? wp[1] : wp[0]);
        bt[OBW1 + idx] = f2bs(v); return;
    }
    idx -= 294912;
    if (idx < 294912){                              // BW2
        int kb = idx / 36864; int r = idx - kb*36864;
        int n = r / 192, k = r - n*192;
        int o = n >> 1, sp = n & 1, i = k >> 1, si = k & 1;
        const float* wp = w2 + ((((kb*96 + i)*96) + o) << 1);
        v = sp == 0 ? (si == 0 ? wp[0] : -wp[1]) : (si == 0 ? wp[1] : wp[0]);
        bt[OBW2 + idx] = f2bs(v); return;
    }
    idx -= 294912;
    {                                               // BE [w(384)][k=s*96+y]
        int w = idx / 192, k = idx - w*192;
        int s = k >= 96, y = k - s*96;
        if (w < 360 && y < 91){
            float th = (float)((y*w) % 360) * 0.017453292519943295f;
            float sv, cv; sincosf(th, &sv, &cv);
            v = (s == 0) ? (y == 0 ? 1.f : 2.f) * cv * R360f
                         : (y == 0 ? 0.f : -2.f*sv*R360f);
        }
        bt[OBE + idx] = f2bs(v);
    }
}

// ---------------------------------------------------------------------------
// gA v2: x panel staged to LDS (bf16) once per block, coalesced, converted
// once. K-loop A-frags are LDS reads; only BA (L2-hot) comes from global.
__global__ __launch_bounds__(256) void gA(const float* __restrict__ x,
                                          short* __restrict__ G1,
                                          const short* __restrict__ BA){
    __shared__ short X[96*392];
    const int b = blockIdx.x, c = b >> 1, hh = (b & 1)*96;
    const int tid = threadIdx.x, wid = tid >> 6, lane = tid & 63;
    const int l15 = lane & 15, q8 = (lane >> 4) << 3, q4 = q8 >> 1;
    const int nt0 = wid*3;
    // stage: 96 rows x 384 cols in float4 chunks (9216), coalesced in col
    #pragma unroll
    for (int i=0;i<36;++i){
        int idx = tid + 256*i;
        int row = idx / 96, ch = idx - row*96;
        int col = ch*4;
        int cc = col < 360 ? col : col - 360;       // wrapped garbage * zero BA
        int h = hh + row; if (h > 179) h = 179;     // rows>=180 dropped at store
        float4 f = *(const float4*)(x + (c*180 + h)*360 + cc);
        PK t; t.s[0]=f2bs(f.x); t.s[1]=f2bs(f.y); t.s[2]=f2bs(f.z); t.s[3]=f2bs(f.w);
        *(uint2*)(X + row*392 + col) = t.u;
    }
    __syncthreads();
    const v4f vz = {0.f,0.f,0.f,0.f};
    v4f acc[6][3];
    #pragma unroll
    for (int i=0;i<6;++i){ acc[i][0]=vz; acc[i][1]=vz; acc[i][2]=vz; }
    for (int ks=0; ks<12; ++ks){
        const int k0 = ks*32 + q8;
        v8s af[6];
        #pragma unroll
        for (int mt=0; mt<6; ++mt)
            af[mt] = ld8s(X + (mt*16 + l15)*392 + k0);
        v8s bf[3];
        #pragma unroll
        for (int j=0;j<3;++j)
            bf[j] = ld8(BA + ((nt0+j)*16 + l15)*384 + k0);
        #pragma unroll
        for (int mt=0; mt<6; ++mt)
            #pragma unroll
            for (int j=0;j<3;++j)
                acc[mt][j] = MFMA(af[mt], bf[j], acc[mt][j]);
    }
    #pragma unroll
    for (int mt=0; mt<6; ++mt){
        int hg = hh + mt*16 + q4;                   // 4-aligned, never straddles 180
        if (hg >= 180) continue;
        #pragma unroll
        for (int j=0;j<3;++j){
            int n = (nt0+j)*16 + l15;
            int s = n >= 96, y = n - s*96;
            *(uint2*)(G1 + (c*96 + y)*360 + s*180 + hg) = pk4(acc[mt][j]);
        }
    }
}

// ---------------------------------------------------------------------------
// gHf v2: G1 panel (shared by all 8 waves as B-operand) staged to LDS once.
__global__ __launch_bounds__(512) void gHf(const short* __restrict__ G1,
                                           short* __restrict__ F2,
                                           const short* __restrict__ BH){
    __shared__ short G[96*392];
    const int c = blockIdx.x;
    const int tid = threadIdx.x, wid = tid >> 6, lane = tid & 63;
    const int l15 = lane & 15, q8 = (lane >> 4) << 3, q4 = q8 >> 1;
    const int mt0 = wid*3;
    // stage: 96 rows x 384 cols bf16 in uint4 chunks (4608), coalesced
    #pragma unroll
    for (int i=0;i<9;++i){
        int idx = tid + 512*i;
        int row = idx / 48, ch = idx - row*48;
        int col = ch*8;
        int cc = col < 360 ? col : col - 360;       // wrapped garbage * zero BH
        *(uint4*)(G + row*392 + col) = *(const uint4*)(G1 + (c*96 + row)*360 + cc);
    }
    __syncthreads();
    const v4f vz = {0.f,0.f,0.f,0.f};
    v4f acc[3][6];
    #pragma unroll
    for (int i=0;i<3;++i)
        #pragma unroll
        for (int j=0;j<6;++j) acc[i][j]=vz;
    for (int ks=0; ks<12; ++ks){
        const int k0 = ks*32 + q8;
        v8s af[3];
        #pragma unroll
        for (int i=0;i<3;++i)
            af[i] = ld8(BH + ((mt0+i)*16 + l15)*384 + k0);
        v8s bf[6];
        #pragma unroll
        for (int j=0;j<6;++j)
            bf[j] = ld8s(G + (j*16 + l15)*392 + k0);
        #pragma unroll
        for (int i=0;i<3;++i)
            #pragma unroll
            for (int j=0;j<6;++j)
                acc[i][j] = MFMA(af[i], bf[j], acc[i][j]);
    }
    #pragma unroll
    for (int i=0;i<3;++i){
        int m = (mt0+i)*16 + q4;
        int s = m >= 192, hp = m - s*192;
        if (hp >= 180) continue;
        const int rb = (2*c + s)*17280 + hp;
        #pragma unroll
        for (int j=0;j<6;++j){
            int y = j*16 + l15;
            *(uint2*)(F2 + rb + y*180) = pk4(acc[i][j]);
        }
    }
}

// ---------------------------------------------------------------------------
// gC v2: wave = 64 modes x 48 outputs (acc[4][3]).
__global__ __launch_bounds__(256) void gC(const short* __restrict__ F2,
                                          short* __restrict__ F3,
                                          const short* __restrict__ BW1,
                                          const short* __restrict__ BW2,
                                          const float* __restrict__ b1,
                                          const float* __restrict__ b2){
    __shared__ short Act[64*200];    // [mode 64][ch2 192 + 8 pad]
    __shared__ short O1[64*200];
    const int mt = blockIdx.x, kb = blockIdx.y, m0 = mt*64;
    const int tid = threadIdx.x;
    #pragma unroll
    for (int i=0;i<6;++i){           // 1536 16B-chunks: transpose F2 -> Act
        int ch = tid + 256*i;
        int qq = ch / 192, rr = ch - qq*192;
        S8 tt; tt.u = *(const uint4*)(F2 + (kb*192 + rr)*17280 + m0 + qq*8);
        #pragma unroll
        for (int j=0;j<8;++j) Act[(qq*8+j)*200 + rr] = tt.s[j];  // consec lanes -> consec elems
    }
    __syncthreads();
    const int wid = tid >> 6, lane = tid & 63, l15 = lane & 15;
    const int q8 = (lane >> 4) << 3, q4 = q8 >> 1;
    const int nt0 = wid*3;                       // wave owns n = [wid*48, wid*48+48)
    const short* bw1 = BW1 + kb*36864;
    const short* bw2 = BW2 + kb*36864;
    const v4f vz = {0.f,0.f,0.f,0.f};
    v4f a1[4][3];
    #pragma unroll
    for (int mr=0;mr<4;++mr){ a1[mr][0]=vz; a1[mr][1]=vz; a1[mr][2]=vz; }
    for (int ks=0; ks<6; ++ks){
        const int k0 = ks*32 + q8;
        v8s af[4];
        #pragma unroll
        for (int mr=0;mr<4;++mr)
            af[mr] = __builtin_bit_cast(v8s, *(const uint4*)(Act + (mr*16 + l15)*200 + k0));
        v8s bf[3];
        #pragma unroll
        for (int j=0;j<3;++j)
            bf[j] = ld8(bw1 + ((nt0+j)*16 + l15)*192 + k0);
        #pragma unroll
        for (int mr=0;mr<4;++mr)
            #pragma unroll
            for (int j=0;j<3;++j)
                a1[mr][j] = MFMA(af[mr], bf[j], a1[mr][j]);
    }
    #pragma unroll
    for (int j=0;j<3;++j){
        int n = (nt0+j)*16 + l15;
        float bv = b1[(kb*96 + (n>>1))*2 + (n&1)];
        #pragma unroll
        for (int mr=0;mr<4;++mr)
            #pragma unroll
            for (int r=0;r<4;++r)
                O1[(mr*16 + q4 + r)*200 + n] = f2bs(fmaxf(a1[mr][j][r] + bv, 0.f));
    }
    __syncthreads();                 // waves read all O1 rows in GEMM2
    v4f a2[4][3];
    #pragma unroll
    for (int mr=0;mr<4;++mr){ a2[mr][0]=vz; a2[mr][1]=vz; a2[mr][2]=vz; }
    for (int ks=0; ks<6; ++ks){
        const int k0 = ks*32 + q8;
        v8s af[4];
        #pragma unroll
        for (int mr=0;mr<4;++mr)
            af[mr] = __builtin_bit_cast(v8s, *(const uint4*)(O1 + (mr*16 + l15)*200 + k0));
        v8s bf[3];
        #pragma unroll
        for (int j=0;j<3;++j)
            bf[j] = ld8(bw2 + ((nt0+j)*16 + l15)*192 + k0);
        #pragma unroll
        for (int mr=0;mr<4;++mr)
            #pragma unroll
            for (int j=0;j<3;++j)
                a2[mr][j] = MFMA(af[mr], bf[j], a2[mr][j]);
    }
    #pragma unroll
    for (int mr=0;mr<4;++mr){
        const int mb = m0 + mr*16 + q4;             // 4-aligned, never straddles 180
        const int y = mb / 180, hp = mb - y*180;
        #pragma unroll
        for (int j=0;j<3;++j){
            int n = (nt0+j)*16 + l15;
            int o = n >> 1, sp = n & 1;
            float bv = b2[(kb*96 + o)*2 + sp];
            v4f vv;
            #pragma unroll
            for (int r=0;r<4;++r) vv[r] = sshrink(a2[mr][j][r] + bv);
            *(uint2*)(F3 + ((kb*96 + o)*96 + y)*360 + sp*180 + hp) = pk4(vv);
        }
    }
}

// ---------------------------------------------------------------------------
// gHi v2: F3 panel (shared by all 8 waves as A-operand) staged to LDS once.
__global__ __launch_bounds__(512) void gHi(const short* __restrict__ F3,
                                           short* __restrict__ Sp,
                                           const short* __restrict__ BHI){
    __shared__ short F[96*392];
    const int c = blockIdx.x;
    const int tid = threadIdx.x, wid = tid >> 6, lane = tid & 63;
    const int l15 = lane & 15, q8 = (lane >> 4) << 3, q4 = q8 >> 1;
    const int nt0 = wid*3;
    #pragma unroll
    for (int i=0;i<9;++i){
        int idx = tid + 512*i;
        int row = idx / 48, ch = idx - row*48;
        int col = ch*8;
        int cc = col < 360 ? col : col - 360;       // wrapped garbage * zero BHI
        *(uint4*)(F + row*392 + col) = *(const uint4*)(F3 + (c*96 + row)*360 + cc);
    }
    __syncthreads();
    const v4f vz = {0.f,0.f,0.f,0.f};
    v4f acc[6][3];
    #pragma unroll
    for (int i=0;i<6;++i){ acc[i][0]=vz; acc[i][1]=vz; acc[i][2]=vz; }
    for (int ks=0; ks<12; ++ks){
        const int k0 = ks*32 + q8;
        v8s af[6];
        #pragma unroll
        for (int i=0;i<6;++i)
            af[i] = ld8s(F + (i*16 + l15)*392 + k0);
        v8s bf[3];
        #pragma unroll
        for (int j=0;j<3;++j)
            bf[j] = ld8(BHI + ((nt0+j)*16 + l15)*384 + k0);
        #pragma unroll
        for (int i=0;i<6;++i)
            #pragma unroll
            for (int j=0;j<3;++j)
                acc[i][j] = MFMA(af[i], bf[j], acc[i][j]);
    }
    #pragma unroll
    for (int j=0;j<3;++j){
        int n = (nt0+j)*16 + l15;
        int s = n >= 192, h = n - s*192;
        if (h >= 180) continue;
        const int rb = (c*180 + h)*192 + s*96;
        #pragma unroll
        for (int i=0;i<6;++i)
            *(uint2*)(Sp + rb + i*16 + q4) = pk4(acc[i][j]);
    }
}

// ---------------------------------------------------------------------------
// gE v4: same wave tile as v3 (64 rows x 96 w, acc[4][6], role-swapped,
// C-init = x), but 4-wave / 256-thread blocks covering 64 rows x 360 w and
// grid 2160. Smaller blocks => 4-5 independent blocks resident per CU in
// staggered phases, so one block's HBM loads/stores overlap another's MFMA
// phase (fixes the 17% occupancy / 2.2 TB/s lockstep of the 8-wave version).
__global__ __launch_bounds__(256) void gE(const float* __restrict__ x,
                                          const short* __restrict__ Sp,
                                          const short* __restrict__ BE,
                                          float* __restrict__ out){
    const int b = blockIdx.x;
    const int tid = threadIdx.x, wid = tid >> 6, lane = tid & 63;
    const int l15 = lane & 15, q8 = (lane >> 4) << 3, q4 = q8 >> 1;
    const int R0 = b*64;                            // block's 64-row group
    const int qt = wid;                             // w-quarter: tiles qt*6..qt*6+5
    v4f acc[4][6];
    #pragma unroll
    for (int r=0;r<4;++r){                          // C-init = x (overlaps GEMM)
        const int rbase = (R0 + r*16 + l15)*360;
        #pragma unroll
        for (int j=0;j<6;++j){
            const int w0 = (qt*6 + j)*16 + q4;
            if (w0 < 360){
                float4 xv = *(const float4*)(x + rbase + w0);
                acc[r][j][0]=xv.x; acc[r][j][1]=xv.y; acc[r][j][2]=xv.z; acc[r][j][3]=xv.w;
            } else {
                acc[r][j] = (v4f){0.f,0.f,0.f,0.f};
            }
        }
    }
    const short* Sr = Sp + (R0 + l15)*192;          // B-role: Spec row per lane
    const short* Bq = BE + (qt*96 + l15)*192;       // A-role: BE row (w) per lane
    #pragma unroll
    for (int ks=0; ks<6; ++ks){
        const int k0 = ks*32 + q8;
        v8s af[6];
        #pragma unroll
        for (int j=0;j<6;++j) af[j] = ld8(Bq + j*3072 + k0);
        v8s bf[4];
        #pragma unroll
        for (int r=0;r<4;++r) bf[r] = ld8(Sr + r*3072 + k0);
        #pragma unroll
        for (int r=0;r<4;++r)
            #pragma unroll
            for (int j=0;j<6;++j)
                acc[r][j] = MFMA(af[j], bf[r], acc[r][j]);
    }
    #pragma unroll
    for (int r=0;r<4;++r){                          // store-only epilogue
        const int rbase = (R0 + r*16 + l15)*360;
        #pragma unroll
        for (int j=0;j<6;++j){
            const int w0 = (qt*6 + j)*16 + q4;
            if (w0 < 360)
                *(float4*)(out + rbase + w0) =
                    make_float4(acc[r][j][0], acc[r][j][1], acc[r][j][2], acc[r][j][3]);
        }
    }
}

// ---------------------------------------------------------------------------
extern "C" void kernel_launch(void* const* d_in, const int* in_sizes, int n_in,
                              void* d_out, int out_size, void* d_ws, size_t ws_size,
                              hipStream_t stream){
    const float* x  = (const float*)d_in[0];
    const float* w1 = (const float*)d_in[1];
    const float* b1 = (const float*)d_in[2];
    const float* w2 = (const float*)d_in[3];
    const float* b2 = (const float*)d_in[4];
    float* out = (float*)d_out;
    short* ws = (short*)d_ws;
    short* B1 = ws;              // G1 then F3 (53.08 MB)
    short* B2 = ws + NBUF;       // F2 then Spec (53.08 MB)

    hipLaunchKernelGGL(bake, dim3((NBAKE+255)/256), dim3(256), 0, stream, w1, w2, ws);
    hipLaunchKernelGGL(gA,  dim3(1536),    dim3(256), 0, stream, x, B1, ws + OBA);
    hipLaunchKernelGGL(gHf, dim3(768),     dim3(512), 0, stream, B1, B2, ws + OBH);
    hipLaunchKernelGGL(gC,  dim3(270, 8),  dim3(256), 0, stream, B2, B1,
                       ws + OBW1, ws + OBW2, b1, b2);
    hipLaunchKernelGGL(gHi, dim3(768),     dim3(512), 0, stream, B1, B2, ws + OBHI);
    hipLaunchKernelGGL(gE,  dim3(2160),    dim3(256), 0, stream, x, B2, ws + OBE, out);
}